// Round 8
// baseline (3086.200 us; speedup 1.0000x reference)
//
#include <hip/hip_runtime.h>

#define B_   8
#define S_   512
#define V_   32000
#define CTX_ 8
#define NC_  512
#define D_   256
#define NH_  4
#define L_   4
#define FF_  512
#define HD_  64
#define BS_  4096   // B_*S_
#define NB   512    // mega-kernel grid (2 blocks/CU, co-resident)

#define FG_F32   1
#define FG_BF16  2
#define FG_RELU  4
#define FG_POS   8
#define FG_NT    16
#define FG_QKV   32

typedef __attribute__((ext_vector_type(8))) short bf16x8;
typedef __attribute__((ext_vector_type(4))) float f32x4;

__device__ inline void gload16(const void* g, void* lds) {
    __builtin_amdgcn_global_load_lds(
        (const __attribute__((address_space(1))) void*)g,
        (__attribute__((address_space(3))) void*)lds, 16, 0, 0);
}

__device__ inline ushort f2b(float f) {   // f32 -> bf16 RNE
    union { float f; unsigned u; } v; v.f = f;
    unsigned u = v.u;
    unsigned r = u + 0x7fffu + ((u >> 16) & 1u);
    return (ushort)(r >> 16);
}

// ---------------------------------------------------------------------------
// Device-scope grid barrier (sense via generation counter). Bounded spin so a
// placement failure produces a wrong answer instead of a hang.
// ---------------------------------------------------------------------------
__device__ __forceinline__ void grid_barrier(unsigned* bar, unsigned* gen) {
    __syncthreads();
    if (threadIdx.x == 0) {
        __threadfence();
        unsigned g = __hip_atomic_load(gen, __ATOMIC_RELAXED, __HIP_MEMORY_SCOPE_AGENT);
        unsigned old = __hip_atomic_fetch_add(bar, 1u, __ATOMIC_ACQ_REL,
                                              __HIP_MEMORY_SCOPE_AGENT);
        if (old == NB - 1) {
            __hip_atomic_store(bar, 0u, __ATOMIC_RELAXED, __HIP_MEMORY_SCOPE_AGENT);
            __hip_atomic_fetch_add(gen, 1u, __ATOMIC_RELEASE, __HIP_MEMORY_SCOPE_AGENT);
        } else {
            int spins = 0;
            while (__hip_atomic_load(gen, __ATOMIC_ACQUIRE,
                                     __HIP_MEMORY_SCOPE_AGENT) == g) {
                __builtin_amdgcn_s_sleep(8);
                if (++spins > (1 << 20)) break;   // ~224ms safety valve
            }
        }
        __threadfence();
    }
    __syncthreads();
}

__global__ void init_kernel(unsigned* bar, unsigned* gen) { *bar = 0u; *gen = 0u; }

// ---------------------------------------------------------------------------
// Phase: one 32x32 transpose+bf16 tile job (flat id, same decode as before)
// ---------------------------------------------------------------------------
__device__ __forceinline__ void d_transpose(
    ushort* smem, int id,
    const float* proj_W, const float* Wq, const float* Wk, const float* Wv,
    const float* Wo, const float* W1, const float* W2, const float* outW,
    ushort* pjWb, ushort* WqkvB, ushort* WoB, ushort* ff1B, ushort* ff2B,
    ushort* Wb)
{
    const float* src; ushort* dst; int K, N, lt;
    if (id < 128)       { src = proj_W; dst = pjWb; K = 512; N = 256; lt = id; }
    else if (id < 896)  { lt = id - 128; int z = lt >> 6; lt &= 63;
                          int which = z / L_, l = z % L_;
                          src = (which == 0 ? Wq : which == 1 ? Wk : Wv) + (size_t)l * 65536;
                          dst = WqkvB + ((size_t)l * 768 + which * 256) * 256;
                          K = 256; N = 256; }
    else if (id < 1152) { lt = id - 896; int l = lt >> 6; lt &= 63;
                          src = Wo + (size_t)l * 65536; dst = WoB + (size_t)l * 65536;
                          K = 256; N = 256; }
    else if (id < 1664) { lt = id - 1152; int l = lt >> 7; lt &= 127;
                          src = W1 + (size_t)l * 131072; dst = ff1B + (size_t)l * 131072;
                          K = 256; N = 512; }
    else if (id < 2176) { lt = id - 1664; int l = lt >> 7; lt &= 127;
                          src = W2 + (size_t)l * 131072; dst = ff2B + (size_t)l * 131072;
                          K = 512; N = 256; }
    else                { lt = id - 2176; src = outW; dst = Wb; K = 256; N = 32000; }
    int ntc = N >> 5;
    int n0 = (lt % ntc) * 32, k0 = (lt / ntc) * 32;
    float* tile = reinterpret_cast<float*>(smem);    // [32][33]
    int tx = threadIdx.x & 31, ty = threadIdx.x >> 5;
    for (int i = ty; i < 32; i += 8)
        tile[i * 33 + tx] = src[(size_t)(k0 + i) * N + n0 + tx];
    __syncthreads();
    for (int i = ty; i < 32; i += 8)
        dst[(size_t)(n0 + i) * K + k0 + tx] = f2b(tile[tx * 33 + i]);
    __syncthreads();
}

// Phase: per-layer setup (cc exact CA reduction + qkv bias pack)
__device__ __forceinline__ void d_setup(
    int l, const float* ca_bv, const float* ca_Wo, const float* ca_bo,
    float* cc, const float* bq, const float* bk, const float* bv, float* qkvb)
{
    int t = threadIdx.x;
    const float* w = ca_Wo + (size_t)l * D_ * D_;
    const float* b = ca_bv + l * D_;
    float acc = 0.f;
    for (int d = 0; d < D_; ++d) acc += b[d] * w[(size_t)d * D_ + t];
    cc[l * D_ + t] = acc + ca_bo[l * D_ + t];
    for (int u = t; u < 768; u += 256) {
        int which = u >> 8, c = u & 255;
        const float* src = which == 0 ? bq : which == 1 ? bk : bv;
        qkvb[l * 768 + u] = src[l * 256 + c];
    }
}

// Phase: embedding for one (b,s) row
__device__ __forceinline__ void d_embed(
    int bs, const int* tok, const float* table, ushort* scores)
{
    int b = bs >> 9, s = bs & 511;
    int j = threadIdx.x;
    float a0 = 0.f, a1 = 0.f;
    #pragma unroll
    for (int c = 0; c < CTX_; ++c) {
        int pos = s + c - (CTX_ - 1);
        int t = (pos < 0) ? 0 : tok[b * S_ + pos];
        const float* row = table + (size_t)t * NC_;
        a0 += row[j];
        a1 += row[j + 256];
    }
    scores[(size_t)bs * NC_ + j]       = f2b(a0 * 0.125f);
    scores[(size_t)bs * NC_ + j + 256] = f2b(a1 * 0.125f);
}

// Phase: layernorm, job = 4-row group (wave per row)
__device__ __forceinline__ void d_ln(
    int j, const float* x, const float* sc, const float* bi, ushort* out)
{
    int row = j * 4 + (threadIdx.x >> 6);
    int lane = threadIdx.x & 63;
    float4 v = *reinterpret_cast<const float4*>(x + (size_t)row * D_ + lane * 4);
    float s = v.x + v.y + v.z + v.w;
    float s2 = v.x * v.x + v.y * v.y + v.z * v.z + v.w * v.w;
    #pragma unroll
    for (int o = 32; o > 0; o >>= 1) {
        s  += __shfl_xor(s, o);
        s2 += __shfl_xor(s2, o);
    }
    float mean = s * (1.f / D_);
    float var = s2 * (1.f / D_) - mean * mean;
    float r = rsqrtf(var + 1e-5f);
    float4 g = *reinterpret_cast<const float4*>(sc + lane * 4);
    float4 bb = *reinterpret_cast<const float4*>(bi + lane * 4);
    ushort4 o4;
    o4.x = f2b((v.x - mean) * r * g.x + bb.x);
    o4.y = f2b((v.y - mean) * r * g.y + bb.y);
    o4.z = f2b((v.z - mean) * r * g.z + bb.z);
    o4.w = f2b((v.w - mean) * r * g.w + bb.w);
    *reinterpret_cast<ushort4*>(out + (size_t)row * D_ + lane * 4) = o4;
}

// ---------------------------------------------------------------------------
// Phase: 64x64 bf16 MFMA GEMM tile (proven gemm_t body, job-indexed)
// ---------------------------------------------------------------------------
template<int K, int TN, int FLAGS>
__device__ __forceinline__ void gemm_phase(
    ushort* smem, int job,
    const ushort* __restrict__ A, const ushort* __restrict__ Bt,
    const float* __restrict__ bias, const float* __restrict__ extra,
    const float* __restrict__ resid, const float* __restrict__ pos,
    float* __restrict__ Cf, ushort* __restrict__ Cb)
{
    constexpr int BM = 64, BN = 64;
    constexpr int MT = 4096 / BM;   // 64
    ushort* As = smem;
    ushort* Bs = smem + BM * 64;
    int mt = job % MT, nt = job / MT;
    int row0 = mt * BM, col0 = nt * BN;
    int t = threadIdx.x, w = t >> 6, lane = t & 63;
    int wr = w >> 1, wc = w & 1;
    int srow = lane >> 3, slot = lane & 7;
    int gcol = (slot ^ srow) * 8;

    f32x4 acc[2][2] = {};
    int sl = lane >> 4;
    int rA0 = wr * 32 + (lane & 15);
    int rB0 = wc * 32 + (lane & 15);

    #pragma unroll
    for (int k0 = 0; k0 < K; k0 += 64) {
        #pragma unroll
        for (int c = 0; c < 2; ++c) {
            int chunk = w * 2 + c;
            gload16(A + (size_t)(row0 + chunk * 8 + srow) * K + k0 + gcol,
                    As + chunk * 512);
            gload16(Bt + (size_t)(col0 + chunk * 8 + srow) * K + k0 + gcol,
                    Bs + chunk * 512);
        }
        __syncthreads();
        #pragma unroll
        for (int kk = 0; kk < 2; ++kk) {
            bf16x8 a[2], b[2];
            #pragma unroll
            for (int m = 0; m < 2; ++m) {
                int rr = rA0 + m * 16;
                a[m] = *reinterpret_cast<const bf16x8*>(
                    As + rr * 64 + (((sl + kk * 4) ^ (rr & 7)) * 8));
            }
            #pragma unroll
            for (int n = 0; n < 2; ++n) {
                int rr = rB0 + n * 16;
                b[n] = *reinterpret_cast<const bf16x8*>(
                    Bs + rr * 64 + (((sl + kk * 4) ^ (rr & 7)) * 8));
            }
            #pragma unroll
            for (int m = 0; m < 2; ++m)
                #pragma unroll
                for (int n = 0; n < 2; ++n)
                    acc[m][n] = __builtin_amdgcn_mfma_f32_16x16x32_bf16(
                        a[m], b[n], acc[m][n], 0, 0, 0);
        }
        __syncthreads();
    }

    int lr = (lane >> 4) * 4;
    int lc = lane & 15;
    #pragma unroll
    for (int n = 0; n < 2; ++n) {
        int col = col0 + wc * 32 + n * 16 + lc;
        float bn = bias ? bias[col] : 0.f;
        float en = extra ? extra[col] : 0.f;
        #pragma unroll
        for (int m = 0; m < 2; ++m) {
            int rbase = row0 + wr * 32 + m * 16 + lr;
            #pragma unroll
            for (int r = 0; r < 4; ++r) {
                int row = rbase + r;
                float v = acc[m][n][r] + bn;
                if constexpr (FLAGS & FG_QKV) {
                    int which = col >> 8;
                    int c2 = col & 255;
                    int hh = c2 >> 6, dd = c2 & 63;
                    int bb = row >> 9, ss = row & 511;
                    if (which == 0) {
                        Cb[((((size_t)bb * NH_ + hh) * S_ + ss) << 6) + dd] =
                            f2b(v * 0.125f);
                    } else if (which == 1) {
                        (Cb + 1048576)[((((size_t)bb * NH_ + hh) * S_ + ss) << 6) + dd] =
                            f2b(v);
                    } else {
                        (Cb + 2097152)[((((size_t)bb * NH_ + hh) * HD_ + dd) << 9) + ss] =
                            f2b(v);
                    }
                } else {
                    if constexpr (FLAGS & FG_POS) v += pos[(size_t)(row & 511) * TN + col];
                    if (extra) v += en;
                    if (resid) v += resid[(size_t)row * TN + col];
                    if constexpr (FLAGS & FG_RELU) v = fmaxf(v, 0.f);
                    if constexpr (FLAGS & FG_BF16)
                        Cb[(size_t)row * TN + col] = f2b(v);
                    if constexpr (FLAGS & FG_F32)
                        Cf[(size_t)row * TN + col] = v;
                }
            }
        }
    }
}

// ---------------------------------------------------------------------------
// Phase: fused flash attention tile (proven attn_kernel body, job-indexed)
// ---------------------------------------------------------------------------
__device__ __forceinline__ void d_attn(
    ushort* smem, int job,
    const ushort* __restrict__ q, const ushort* __restrict__ k,
    const ushort* __restrict__ vT, ushort* __restrict__ pv)
{
    int bh = job & 31, qt = job >> 5;
    ushort* Ks = smem;
    ushort* Vs = smem + 4096;
    ushort* Ps = smem + 8192;
    int t = threadIdx.x, w = t >> 6, lane = t & 63;
    int srow = lane >> 3, slot = lane & 7;
    int gcol = (slot ^ srow) * 8;
    int sl = lane >> 4, lc = lane & 15;

    const ushort* Qp = q + ((size_t)bh * S_ + qt * 64) * HD_;
    const ushort* Kp = k + (size_t)bh * S_ * HD_;
    const ushort* Vp = vT + (size_t)bh * HD_ * S_;

    int qrow = w * 16 + lc;
    bf16x8 qf0 = *reinterpret_cast<const bf16x8*>(Qp + qrow * 64 + sl * 8);
    bf16x8 qf1 = *reinterpret_cast<const bf16x8*>(Qp + qrow * 64 + sl * 8 + 32);

    f32x4 o[4] = {};
    float m_r[4], l_r[4];
    #pragma unroll
    for (int r = 0; r < 4; ++r) { m_r[r] = -1e30f; l_r[r] = 0.f; }
    int row_abs = qt * 64 + w * 16 + sl * 4;

    for (int kt = 0; kt <= qt; ++kt) {
        #pragma unroll
        for (int c = 0; c < 2; ++c) {
            int chunk = w * 2 + c;
            gload16(Kp + (size_t)(kt * 64 + chunk * 8 + srow) * 64 + gcol,
                    Ks + chunk * 512);
            gload16(Vp + (size_t)(chunk * 8 + srow) * 512 + kt * 64 + gcol,
                    Vs + chunk * 512);
        }
        __syncthreads();

        f32x4 sa[4] = {};
        #pragma unroll
        for (int n = 0; n < 4; ++n) {
            int rB = n * 16 + lc;
            bf16x8 b0 = *reinterpret_cast<const bf16x8*>(
                Ks + rB * 64 + ((sl ^ (rB & 7)) * 8));
            bf16x8 b1 = *reinterpret_cast<const bf16x8*>(
                Ks + rB * 64 + (((sl + 4) ^ (rB & 7)) * 8));
            sa[n] = __builtin_amdgcn_mfma_f32_16x16x32_bf16(qf0, b0, sa[n], 0, 0, 0);
            sa[n] = __builtin_amdgcn_mfma_f32_16x16x32_bf16(qf1, b1, sa[n], 0, 0, 0);
        }
        if (kt == qt) {
            #pragma unroll
            for (int n = 0; n < 4; ++n) {
                int col = kt * 64 + n * 16 + lc;
                #pragma unroll
                for (int r = 0; r < 4; ++r)
                    if (col > row_abs + r) sa[n][r] = -1e30f;
            }
        }
        float psum[4];
        #pragma unroll
        for (int r = 0; r < 4; ++r) {
            float vm = fmaxf(fmaxf(sa[0][r], sa[1][r]), fmaxf(sa[2][r], sa[3][r]));
            vm = fmaxf(vm, __shfl_xor(vm, 1));
            vm = fmaxf(vm, __shfl_xor(vm, 2));
            vm = fmaxf(vm, __shfl_xor(vm, 4));
            vm = fmaxf(vm, __shfl_xor(vm, 8));
            float mn = fmaxf(m_r[r], vm);
            float scl = __expf(m_r[r] - mn);
            m_r[r] = mn;
            l_r[r] *= scl;
            #pragma unroll
            for (int n = 0; n < 4; ++n) o[n][r] *= scl;
            psum[r] = 0.f;
        }
        ushort* Pw = Ps + w * 1024;
        #pragma unroll
        for (int n = 0; n < 4; ++n) {
            #pragma unroll
            for (int r = 0; r < 4; ++r) {
                float p = __expf(sa[n][r] - m_r[r]);
                psum[r] += p;
                int prow = sl * 4 + r;
                int pcol = n * 16 + lc;
                int pslot = pcol >> 3;
                Pw[prow * 64 + ((pslot ^ (prow & 7)) * 8) + (pcol & 7)] = f2b(p);
            }
        }
        #pragma unroll
        for (int r = 0; r < 4; ++r) {
            float s = psum[r];
            s += __shfl_xor(s, 1);
            s += __shfl_xor(s, 2);
            s += __shfl_xor(s, 4);
            s += __shfl_xor(s, 8);
            l_r[r] += s;
        }
        int arow = lc;
        bf16x8 pa0 = *reinterpret_cast<const bf16x8*>(
            Pw + arow * 64 + ((sl ^ (arow & 7)) * 8));
        bf16x8 pa1 = *reinterpret_cast<const bf16x8*>(
            Pw + arow * 64 + (((sl + 4) ^ (arow & 7)) * 8));
        #pragma unroll
        for (int n = 0; n < 4; ++n) {
            int rB = n * 16 + lc;
            bf16x8 v0 = *reinterpret_cast<const bf16x8*>(
                Vs + rB * 64 + ((sl ^ (rB & 7)) * 8));
            bf16x8 v1 = *reinterpret_cast<const bf16x8*>(
                Vs + rB * 64 + (((sl + 4) ^ (rB & 7)) * 8));
            o[n] = __builtin_amdgcn_mfma_f32_16x16x32_bf16(pa0, v0, o[n], 0, 0, 0);
            o[n] = __builtin_amdgcn_mfma_f32_16x16x32_bf16(pa1, v1, o[n], 0, 0, 0);
        }
        __syncthreads();
    }

    int bb = bh >> 2, hh = bh & 3;
    #pragma unroll
    for (int r = 0; r < 4; ++r) {
        float inv = 1.f / l_r[r];
        int ss = qt * 64 + w * 16 + sl * 4 + r;
        #pragma unroll
        for (int n = 0; n < 4; ++n) {
            int dd = n * 16 + lc;
            pv[((size_t)bb * S_ + ss) * D_ + hh * HD_ + dd] = f2b(o[n][r] * inv);
        }
    }
}

// ---------------------------------------------------------------------------
// MEGA persistent kernel: everything except the logits GEMM.
// ---------------------------------------------------------------------------
__global__ __launch_bounds__(256, 2) void mega_kernel(
    const int* tok, const float* ram,
    const float* proj_W, const float* proj_b, const float* pos_emb,
    const float* sa_Wq, const float* sa_Wk, const float* sa_Wv, const float* sa_Wo,
    const float* sa_bq, const float* sa_bk, const float* sa_bv, const float* sa_bo,
    const float* ca_Wo, const float* ca_bv, const float* ca_bo,
    const float* ln1_s, const float* ln1_b, const float* ln3_s, const float* ln3_b,
    const float* ff_W1, const float* ff_b1, const float* ff_W2, const float* ff_b2,
    const float* out_W,
    float* x, float* cc, ushort* xb, ushort* Wb,
    ushort* sc_b, ushort* h_b, ushort* qkv3, ushort* pv_b, ushort* ffh_b,
    ushort* pjWb, ushort* WqkvB, ushort* WoB, ushort* ff1B, ushort* ff2B,
    float* qkvb, unsigned* bar, unsigned* gen)
{
    __shared__ __align__(16) ushort smem[12288];   // 24 KB
    int bid = blockIdx.x;

    // phase 0: transposes (10176) + setup (4) + embed (4096)
    for (int j = bid; j < 14276; j += NB) {
        if (j < 10176)
            d_transpose(smem, j, proj_W, sa_Wq, sa_Wk, sa_Wv, sa_Wo,
                        ff_W1, ff_W2, out_W, pjWb, WqkvB, WoB, ff1B, ff2B, Wb);
        else if (j < 10180)
            d_setup(j - 10176, ca_bv, ca_Wo, ca_bo, cc, sa_bq, sa_bk, sa_bv, qkvb);
        else
            d_embed(j - 10180, tok, ram, sc_b);
    }
    grid_barrier(bar, gen);

    // x = scores @ proj_W + proj_b + pos_emb
    if (bid < 256)
        gemm_phase<512, 256, FG_F32 | FG_POS>(smem, bid, sc_b, pjWb, proj_b,
            nullptr, nullptr, pos_emb, x, nullptr);
    grid_barrier(bar, gen);

    for (int l = 0; l < L_; ++l) {
        for (int j = bid; j < 1024; j += NB)
            d_ln(j, x, ln1_s + l * D_, ln1_b + l * D_, h_b);
        grid_barrier(bar, gen);

        for (int j = bid; j < 768; j += NB)
            gemm_phase<256, 768, FG_QKV>(smem, j, h_b,
                WqkvB + (size_t)l * 196608, qkvb + l * 768,
                nullptr, nullptr, nullptr, nullptr, qkv3);
        grid_barrier(bar, gen);

        if (bid < 256)
            d_attn(smem, bid, qkv3, qkv3 + 1048576, qkv3 + 2097152, pv_b);
        grid_barrier(bar, gen);

        if (bid < 256)
            gemm_phase<256, 256, FG_F32>(smem, bid, pv_b,
                WoB + (size_t)l * 65536, sa_bo + l * D_,
                cc + l * D_, x, nullptr, x, nullptr);
        grid_barrier(bar, gen);

        for (int j = bid; j < 1024; j += NB)
            d_ln(j, x, ln3_s + l * D_, ln3_b + l * D_, h_b);
        grid_barrier(bar, gen);

        if (bid < 512)
            gemm_phase<256, 512, FG_BF16 | FG_RELU>(smem, bid, h_b,
                ff1B + (size_t)l * 131072, ff_b1 + l * FF_,
                nullptr, nullptr, nullptr, nullptr, ffh_b);
        grid_barrier(bar, gen);

        if (l < L_ - 1) {
            if (bid < 256)
                gemm_phase<512, 256, FG_F32>(smem, bid, ffh_b,
                    ff2B + (size_t)l * 131072, ff_b2 + l * D_,
                    nullptr, x, nullptr, x, nullptr);
            grid_barrier(bar, gen);
        } else {
            if (bid < 256)
                gemm_phase<512, 256, FG_BF16>(smem, bid, ffh_b,
                    ff2B + (size_t)l * 131072, ff_b2 + l * D_,
                    nullptr, x, nullptr, nullptr, xb);
        }
    }
}

// ---------------------------------------------------------------------------
// Logits GEMM (unchanged proven kernel): 128x128 tile, LDS-staged NT epilogue
// ---------------------------------------------------------------------------
template<int BM, int BN, int K, int TN, int FLAGS>
__global__ __launch_bounds__(256) void gemm_t(
    const ushort* __restrict__ A, const ushort* __restrict__ Bt,
    const float* __restrict__ bias, float* __restrict__ Cf)
{
    constexpr int WM = BM / 32;
    constexpr int WN = BN / 32;
    constexpr int MT = 4096 / BM;
    constexpr int NWG = MT * (TN / BN);
    __shared__ ushort smem[(BM + BN) * 64];
    ushort* As = smem;
    ushort* Bs = smem + BM * 64;
    int bid = blockIdx.x;
    int swz = bid;
    if constexpr ((NWG & 7) == 0) {
        constexpr int cpx = NWG >> 3;
        swz = (bid & 7) * cpx + (bid >> 3);
    }
    int mt = swz % MT, nt = swz / MT;
    int row0 = mt * BM, col0 = nt * BN;
    int t = threadIdx.x, w = t >> 6, lane = t & 63;
    int wr = w >> 1, wc = w & 1;
    int srow = lane >> 3, slot = lane & 7;
    int gcol = (slot ^ srow) * 8;

    f32x4 acc[WM][WN] = {};
    int sl = lane >> 4;
    int rA0 = wr * (BM / 2) + (lane & 15);
    int rB0 = wc * (BN / 2) + (lane & 15);

    #pragma unroll
    for (int k0 = 0; k0 < K; k0 += 64) {
        #pragma unroll
        for (int c = 0; c < BM / 32; ++c) {
            int chunk = w * (BM / 32) + c;
            gload16(A + (size_t)(row0 + chunk * 8 + srow) * K + k0 + gcol,
                    As + chunk * 512);
        }
        #pragma unroll
        for (int c = 0; c < BN / 32; ++c) {
            int chunk = w * (BN / 32) + c;
            gload16(Bt + (size_t)(col0 + chunk * 8 + srow) * K + k0 + gcol,
                    Bs + chunk * 512);
        }
        __syncthreads();
        #pragma unroll
        for (int kk = 0; kk < 2; ++kk) {
            bf16x8 a[WM], b[WN];
            #pragma unroll
            for (int m = 0; m < WM; ++m) {
                int rr = rA0 + m * 16;
                a[m] = *reinterpret_cast<const bf16x8*>(
                    As + rr * 64 + (((sl + kk * 4) ^ (rr & 7)) * 8));
            }
            #pragma unroll
            for (int n = 0; n < WN; ++n) {
                int rr = rB0 + n * 16;
                b[n] = *reinterpret_cast<const bf16x8*>(
                    Bs + rr * 64 + (((sl + kk * 4) ^ (rr & 7)) * 8));
            }
            #pragma unroll
            for (int m = 0; m < WM; ++m)
                #pragma unroll
                for (int n = 0; n < WN; ++n)
                    acc[m][n] = __builtin_amdgcn_mfma_f32_16x16x32_bf16(
                        a[m], b[n], acc[m][n], 0, 0, 0);
        }
        __syncthreads();
    }

    int lr = (lane >> 4) * 4;
    int lc = lane & 15;
    // C half-tile through LDS -> coalesced f32x4 nontemporal stores
    float* Ct = reinterpret_cast<float*>(smem);
    #pragma unroll
    for (int p = 0; p < 2; ++p) {
        __syncthreads();
        if (wr == p) {
            #pragma unroll
            for (int n = 0; n < WN; ++n) {
                int colL = wc * (BN / 2) + n * 16 + lc;
                float bn = bias[col0 + colL];
                #pragma unroll
                for (int m = 0; m < WM; ++m)
                    #pragma unroll
                    for (int r = 0; r < 4; ++r)
                        Ct[(m * 16 + lr + r) * BN + colL] = acc[m][n][r] + bn;
            }
        }
        __syncthreads();
        constexpr int NV4 = (BM / 2) * (BN / 4);
        #pragma unroll
        for (int j = 0; j < NV4 / 256; ++j) {
            int idx = t + j * 256;
            int rl = idx / (BN / 4);
            int c4 = idx % (BN / 4);
            f32x4 v4 = reinterpret_cast<const f32x4*>(Ct)[idx];
            __builtin_nontemporal_store(v4,
                reinterpret_cast<f32x4*>(
                    &Cf[(size_t)(row0 + p * (BM / 2) + rl) * TN + col0 + c4 * 4]));
        }
    }
}

// ===========================================================================
extern "C" void kernel_launch(void* const* d_in, const int* in_sizes, int n_in,
                              void* d_out, int out_size, void* d_ws, size_t ws_size,
                              hipStream_t stream)
{
    const int*   tok     = (const int*)  d_in[0];
    const float* ram     = (const float*)d_in[1];
    const float* proj_W  = (const float*)d_in[2];
    const float* proj_b  = (const float*)d_in[3];
    const float* pos_emb = (const float*)d_in[4];
    const float* sa_Wq   = (const float*)d_in[5];
    const float* sa_Wk   = (const float*)d_in[6];
    const float* sa_Wv   = (const float*)d_in[7];
    const float* sa_Wo   = (const float*)d_in[8];
    const float* sa_bq   = (const float*)d_in[9];
    const float* sa_bk   = (const float*)d_in[10];
    const float* sa_bv   = (const float*)d_in[11];
    const float* sa_bo   = (const float*)d_in[12];
    const float* ca_Wo   = (const float*)d_in[16];
    const float* ca_bv   = (const float*)d_in[19];
    const float* ca_bo   = (const float*)d_in[20];
    const float* ln1_s   = (const float*)d_in[21];
    const float* ln1_b   = (const float*)d_in[22];
    const float* ln3_s   = (const float*)d_in[25];
    const float* ln3_b   = (const float*)d_in[26];
    const float* ff_W1   = (const float*)d_in[27];
    const float* ff_b1   = (const float*)d_in[28];
    const float* ff_W2   = (const float*)d_in[29];
    const float* ff_b2   = (const float*)d_in[30];
    const float* out_W   = (const float*)d_in[31];
    const float* out_b   = (const float*)d_in[32];

    float* out = (float*)d_out;
    float* ws  = (float*)d_ws;

    // ws: x | cc | xb | Wb | bar,gen
    float*    x   = ws;                            // BS_*D_ f32
    float*    cc  = ws + (size_t)BS_ * D_;         // L_*D_ f32
    ushort*   xb  = (ushort*)(cc + L_ * D_);       // BS_*D_ bf16
    ushort*   Wb  = xb + (size_t)BS_ * D_;         // V_*D_ bf16
    unsigned* bar = (unsigned*)(Wb + (size_t)V_ * D_);
    unsigned* gen = bar + 1;

    // d_out scratch (fully overwritten by the logits GEMM)
    ushort* sc_b  = (ushort*)out;                // 2,097,152
    ushort* h_b   = sc_b + 2097152;              // 1,048,576
    ushort* qkv3  = h_b + 1048576;               // 3,145,728 (q|k|vT)
    ushort* pv_b  = qkv3 + 3145728;              // 1,048,576
    ushort* ffh_b = pv_b + 1048576;              // 2,097,152
    ushort* pjWb  = ffh_b + 2097152;             // 131,072
    ushort* WqkvB = pjWb + 131072;               // 786,432
    ushort* WoB   = WqkvB + 786432;              // 262,144
    ushort* ff1B  = WoB + 262144;                // 524,288
    ushort* ff2B  = ff1B + 524288;               // 524,288
    float*  qkvb  = (float*)(ff2B + 524288);     // 4096 f32

    init_kernel<<<1, 1, 0, stream>>>(bar, gen);
    mega_kernel<<<NB, 256, 0, stream>>>(
        tok, ram, proj_W, proj_b, pos_emb,
        sa_Wq, sa_Wk, sa_Wv, sa_Wo, sa_bq, sa_bk, sa_bv, sa_bo,
        ca_Wo, ca_bv, ca_bo, ln1_s, ln1_b, ln3_s, ln3_b,
        ff_W1, ff_b1, ff_W2, ff_b2, out_W,
        x, cc, xb, Wb, sc_b, h_b, qkv3, pv_b, ffh_b,
        pjWb, WqkvB, WoB, ff1B, ff2B, qkvb, bar, gen);
    gemm_t<128, 128, 256, 32000, FG_F32 | FG_NT><<<8000, 256, 0, stream>>>(
        xb, Wb, out_b, out);
}

// Round 9
// 400.043 us; speedup vs baseline: 7.7147x; 7.7147x over previous
//
#include <hip/hip_runtime.h>

#define B_   8
#define S_   512
#define V_   32000
#define CTX_ 8
#define NC_  512
#define D_   256
#define NH_  4
#define L_   4
#define FF_  512
#define HD_  64
#define BS_  4096   // B_*S_

#define FG_F32   1
#define FG_BF16  2
#define FG_RELU  4
#define FG_POS   8
#define FG_NT    16
#define FG_QKV   32

typedef __attribute__((ext_vector_type(8))) short bf16x8;
typedef __attribute__((ext_vector_type(4))) float f32x4;

__device__ inline void gload16(const void* g, void* lds) {
    __builtin_amdgcn_global_load_lds(
        (const __attribute__((address_space(1))) void*)g,
        (__attribute__((address_space(3))) void*)lds, 16, 0, 0);
}

__device__ inline ushort f2b(float f) {   // f32 -> bf16 RNE
    union { float f; unsigned u; } v; v.f = f;
    unsigned u = v.u;
    unsigned r = u + 0x7fffu + ((u >> 16) & 1u);
    return (ushort)(r >> 16);
}

// ---------------------------------------------------------------------------
// Prologue (ONE launch): flat job grid.
//   id < 10176          : 32x32 weight transpose+bf16 tile
//   10176 <= id < 10180 : per-layer setup (cc exact CA reduction + bias pack)
//   id >= 10180         : embedding row (b,s)
// ---------------------------------------------------------------------------
__global__ __launch_bounds__(256) void prologue_kernel(
    const int* __restrict__ tok, const float* __restrict__ ram,
    const float* __restrict__ proj_W, const float* __restrict__ Wq,
    const float* __restrict__ Wk, const float* __restrict__ Wv,
    const float* __restrict__ Wo, const float* __restrict__ W1,
    const float* __restrict__ W2, const float* __restrict__ outW,
    const float* __restrict__ ca_bv, const float* __restrict__ ca_Wo,
    const float* __restrict__ ca_bo, const float* __restrict__ bq,
    const float* __restrict__ bk, const float* __restrict__ bv,
    ushort* __restrict__ pjWb, ushort* __restrict__ WqkvB,
    ushort* __restrict__ WoB, ushort* __restrict__ ff1B,
    ushort* __restrict__ ff2B, ushort* __restrict__ Wb,
    float* __restrict__ cc, float* __restrict__ qkvb,
    ushort* __restrict__ scores)
{
    __shared__ float tile[32 * 33];
    int id = blockIdx.x;
    int t = threadIdx.x;
    if (id < 10176) {
        const float* src; ushort* dst; int K, N, lt;
        if (id < 128)       { src = proj_W; dst = pjWb; K = 512; N = 256; lt = id; }
        else if (id < 896)  { lt = id - 128; int z = lt >> 6; lt &= 63;
                              int which = z / L_, l = z % L_;
                              src = (which == 0 ? Wq : which == 1 ? Wk : Wv) + (size_t)l * 65536;
                              dst = WqkvB + ((size_t)l * 768 + which * 256) * 256;
                              K = 256; N = 256; }
        else if (id < 1152) { lt = id - 896; int l = lt >> 6; lt &= 63;
                              src = Wo + (size_t)l * 65536; dst = WoB + (size_t)l * 65536;
                              K = 256; N = 256; }
        else if (id < 1664) { lt = id - 1152; int l = lt >> 7; lt &= 127;
                              src = W1 + (size_t)l * 131072; dst = ff1B + (size_t)l * 131072;
                              K = 256; N = 512; }
        else if (id < 2176) { lt = id - 1664; int l = lt >> 7; lt &= 127;
                              src = W2 + (size_t)l * 131072; dst = ff2B + (size_t)l * 131072;
                              K = 512; N = 256; }
        else                { lt = id - 2176; src = outW; dst = Wb; K = 256; N = 32000; }
        int ntc = N >> 5;
        int n0 = (lt % ntc) * 32, k0 = (lt / ntc) * 32;
        int tx = t & 31, ty = t >> 5;
        for (int i = ty; i < 32; i += 8)
            tile[i * 33 + tx] = src[(size_t)(k0 + i) * N + n0 + tx];
        __syncthreads();
        for (int i = ty; i < 32; i += 8)
            dst[(size_t)(n0 + i) * K + k0 + tx] = f2b(tile[tx * 33 + i]);
    } else if (id < 10180) {
        int l = id - 10176;
        const float* w = ca_Wo + (size_t)l * D_ * D_;
        const float* b = ca_bv + l * D_;
        float acc = 0.f;
        for (int d = 0; d < D_; ++d) acc += b[d] * w[(size_t)d * D_ + t];
        cc[l * D_ + t] = acc + ca_bo[l * D_ + t];
        for (int u = t; u < 768; u += 256) {
            int which = u >> 8, c = u & 255;
            const float* src = which == 0 ? bq : which == 1 ? bk : bv;
            qkvb[l * 768 + u] = src[l * 256 + c];
        }
    } else {
        int bs = id - 10180;
        int b = bs >> 9, s = bs & 511;
        float a0 = 0.f, a1 = 0.f;
        #pragma unroll
        for (int c = 0; c < CTX_; ++c) {
            int pos = s + c - (CTX_ - 1);
            int tk = (pos < 0) ? 0 : tok[b * S_ + pos];
            const float* row = ram + (size_t)tk * NC_;
            a0 += row[t];
            a1 += row[t + 256];
        }
        scores[(size_t)bs * NC_ + t]       = f2b(a0 * 0.125f);
        scores[(size_t)bs * NC_ + t + 256] = f2b(a1 * 0.125f);
    }
}

// ---------------------------------------------------------------------------
// LayerNorm f32 -> bf16, one WAVE per row (4 rows / 256-thread block)
// ---------------------------------------------------------------------------
__global__ __launch_bounds__(256) void ln_bf16_kernel(
    const float* __restrict__ x, const float* __restrict__ sc,
    const float* __restrict__ bi, ushort* __restrict__ out)
{
    int row = blockIdx.x * 4 + (threadIdx.x >> 6);
    int lane = threadIdx.x & 63;
    float4 v = *reinterpret_cast<const float4*>(x + (size_t)row * D_ + lane * 4);
    float s = v.x + v.y + v.z + v.w;
    float s2 = v.x * v.x + v.y * v.y + v.z * v.z + v.w * v.w;
    #pragma unroll
    for (int o = 32; o > 0; o >>= 1) {
        s  += __shfl_xor(s, o);
        s2 += __shfl_xor(s2, o);
    }
    float mean = s * (1.f / D_);
    float var = s2 * (1.f / D_) - mean * mean;
    float r = rsqrtf(var + 1e-5f);
    float4 g = *reinterpret_cast<const float4*>(sc + lane * 4);
    float4 bb = *reinterpret_cast<const float4*>(bi + lane * 4);
    ushort4 o4;
    o4.x = f2b((v.x - mean) * r * g.x + bb.x);
    o4.y = f2b((v.y - mean) * r * g.y + bb.y);
    o4.z = f2b((v.z - mean) * r * g.z + bb.z);
    o4.w = f2b((v.w - mean) * r * g.w + bb.w);
    *reinterpret_cast<ushort4*>(out + (size_t)row * D_ + lane * 4) = o4;
}

// ---------------------------------------------------------------------------
// Templated bf16 MFMA GEMM.  A[4096][K] bf16, Bt[TN][K] bf16.
// 4 waves (2x2).  BK=64.  LDS XOR-swizzled (T2, both-sides rule #21).
// FG_NT: epilogue stages C through LDS -> coalesced f32x4 nontemporal stores.
// ---------------------------------------------------------------------------
template<int BM, int BN, int K, int TN, int FLAGS>
__global__ __launch_bounds__(256) void gemm_t(
    const ushort* __restrict__ A, const ushort* __restrict__ Bt,
    const float* __restrict__ bias, const float* __restrict__ extra,
    const float* __restrict__ resid, const float* __restrict__ pos,
    float* __restrict__ Cf, ushort* __restrict__ Cb)
{
    constexpr int WM = BM / 32;
    constexpr int WN = BN / 32;
    constexpr int MT = 4096 / BM;
    constexpr int NWG = MT * (TN / BN);
    __shared__ ushort smem[(BM + BN) * 64];
    ushort* As = smem;
    ushort* Bs = smem + BM * 64;
    int bid = blockIdx.x;
    int swz = bid;
    if constexpr ((NWG & 7) == 0) {
        constexpr int cpx = NWG >> 3;
        swz = (bid & 7) * cpx + (bid >> 3);
    }
    int mt = swz % MT, nt = swz / MT;
    int row0 = mt * BM, col0 = nt * BN;
    int t = threadIdx.x, w = t >> 6, lane = t & 63;
    int wr = w >> 1, wc = w & 1;
    int srow = lane >> 3, slot = lane & 7;
    int gcol = (slot ^ srow) * 8;          // inverse-swizzled global col

    f32x4 acc[WM][WN] = {};
    int sl = lane >> 4;
    int rA0 = wr * (BM / 2) + (lane & 15);
    int rB0 = wc * (BN / 2) + (lane & 15);

    #pragma unroll
    for (int k0 = 0; k0 < K; k0 += 64) {
        #pragma unroll
        for (int c = 0; c < BM / 32; ++c) {
            int chunk = w * (BM / 32) + c;
            gload16(A + (size_t)(row0 + chunk * 8 + srow) * K + k0 + gcol,
                    As + chunk * 512);
        }
        #pragma unroll
        for (int c = 0; c < BN / 32; ++c) {
            int chunk = w * (BN / 32) + c;
            gload16(Bt + (size_t)(col0 + chunk * 8 + srow) * K + k0 + gcol,
                    Bs + chunk * 512);
        }
        __syncthreads();
        #pragma unroll
        for (int kk = 0; kk < 2; ++kk) {
            bf16x8 a[WM], b[WN];
            #pragma unroll
            for (int m = 0; m < WM; ++m) {
                int rr = rA0 + m * 16;
                a[m] = *reinterpret_cast<const bf16x8*>(
                    As + rr * 64 + (((sl + kk * 4) ^ (rr & 7)) * 8));
            }
            #pragma unroll
            for (int n = 0; n < WN; ++n) {
                int rr = rB0 + n * 16;
                b[n] = *reinterpret_cast<const bf16x8*>(
                    Bs + rr * 64 + (((sl + kk * 4) ^ (rr & 7)) * 8));
            }
            #pragma unroll
            for (int m = 0; m < WM; ++m)
                #pragma unroll
                for (int n = 0; n < WN; ++n)
                    acc[m][n] = __builtin_amdgcn_mfma_f32_16x16x32_bf16(
                        a[m], b[n], acc[m][n], 0, 0, 0);
        }
        __syncthreads();
    }

    int lr = (lane >> 4) * 4;
    int lc = lane & 15;

    if constexpr (FLAGS & FG_NT) {
        // C half-tile through LDS -> coalesced f32x4 nontemporal stores.
        float* Ct = reinterpret_cast<float*>(smem);   // (BM/2)*BN f32 == smem size
        #pragma unroll
        for (int p = 0; p < 2; ++p) {
            __syncthreads();
            if (wr == p) {
                #pragma unroll
                for (int n = 0; n < WN; ++n) {
                    int colL = wc * (BN / 2) + n * 16 + lc;
                    float bn = bias[col0 + colL];
                    #pragma unroll
                    for (int m = 0; m < WM; ++m)
                        #pragma unroll
                        for (int r = 0; r < 4; ++r)
                            Ct[(m * 16 + lr + r) * BN + colL] = acc[m][n][r] + bn;
                }
            }
            __syncthreads();
            constexpr int NV4 = (BM / 2) * (BN / 4);
            #pragma unroll
            for (int j = 0; j < NV4 / 256; ++j) {
                int idx = t + j * 256;
                int rl = idx / (BN / 4);
                int c4 = idx % (BN / 4);
                f32x4 v4 = reinterpret_cast<const f32x4*>(Ct)[idx];
                __builtin_nontemporal_store(v4,
                    reinterpret_cast<f32x4*>(
                        &Cf[(size_t)(row0 + p * (BM / 2) + rl) * TN + col0 + c4 * 4]));
            }
        }
        return;
    }

    #pragma unroll
    for (int n = 0; n < WN; ++n) {
        int col = col0 + wc * (BN / 2) + n * 16 + lc;
        float bn = bias ? bias[col] : 0.f;
        float en = extra ? extra[col] : 0.f;
        #pragma unroll
        for (int m = 0; m < WM; ++m) {
            int rbase = row0 + wr * (BM / 2) + m * 16 + lr;
            #pragma unroll
            for (int r = 0; r < 4; ++r) {
                int row = rbase + r;
                float v = acc[m][n][r] + bn;
                if constexpr (FLAGS & FG_QKV) {
                    int which = col >> 8;
                    int c2 = col & 255;
                    int hh = c2 >> 6, dd = c2 & 63;
                    int bb = row >> 9, ss = row & 511;
                    if (which == 0) {
                        Cb[((((size_t)bb * NH_ + hh) * S_ + ss) << 6) + dd] =
                            f2b(v * 0.125f);
                    } else if (which == 1) {
                        (Cb + 1048576)[((((size_t)bb * NH_ + hh) * S_ + ss) << 6) + dd] =
                            f2b(v);
                    } else {
                        (Cb + 2097152)[((((size_t)bb * NH_ + hh) * HD_ + dd) << 9) + ss] =
                            f2b(v);
                    }
                } else {
                    if constexpr (FLAGS & FG_POS) v += pos[(size_t)(row & 511) * TN + col];
                    if (extra) v += en;
                    if (resid) v += resid[(size_t)row * TN + col];
                    if constexpr (FLAGS & FG_RELU) v = fmaxf(v, 0.f);
                    if constexpr (FLAGS & FG_BF16)
                        Cb[(size_t)row * TN + col] = f2b(v);
                    if constexpr (FLAGS & FG_F32)
                        Cf[(size_t)row * TN + col] = v;
                }
            }
        }
    }
}

// ---------------------------------------------------------------------------
// Fused flash attention, K/V double-buffered: one block per (q-tile, bh).
// 4 waves x 16 q-rows. q,k head-major [bh][s][64] bf16 (q pre-scaled 1/8);
// v transposed [bh][d][s]. One barrier per kt; next tile prefetched before
// compute (loads drain at the next barrier).
// ---------------------------------------------------------------------------
__global__ __launch_bounds__(256) void attn_kernel(
    const ushort* __restrict__ q, const ushort* __restrict__ k,
    const ushort* __restrict__ vT, ushort* __restrict__ pv)
{
    int qt = blockIdx.x, bh = blockIdx.y;
    __shared__ ushort smem[20480];       // 2x(Ks 4096 + Vs 4096) + Ps 4096
    ushort* Ps = smem + 16384;
    int t = threadIdx.x, w = t >> 6, lane = t & 63;
    int srow = lane >> 3, slot = lane & 7;
    int gcol = (slot ^ srow) * 8;
    int sl = lane >> 4, lc = lane & 15;

    const ushort* Qp = q + ((size_t)bh * S_ + qt * 64) * HD_;
    const ushort* Kp = k + (size_t)bh * S_ * HD_;
    const ushort* Vp = vT + (size_t)bh * HD_ * S_;

    int qrow = w * 16 + lc;
    bf16x8 qf0 = *reinterpret_cast<const bf16x8*>(Qp + qrow * 64 + sl * 8);
    bf16x8 qf1 = *reinterpret_cast<const bf16x8*>(Qp + qrow * 64 + sl * 8 + 32);

    f32x4 o[4] = {};
    float m_r[4], l_r[4];
    #pragma unroll
    for (int r = 0; r < 4; ++r) { m_r[r] = -1e30f; l_r[r] = 0.f; }
    int row_abs = qt * 64 + w * 16 + sl * 4;

    // stage kt=0 into buffer 0
    {
        ushort* Ks = smem;
        ushort* Vs = smem + 4096;
        #pragma unroll
        for (int c = 0; c < 2; ++c) {
            int chunk = w * 2 + c;
            gload16(Kp + (size_t)(chunk * 8 + srow) * 64 + gcol, Ks + chunk * 512);
            gload16(Vp + (size_t)(chunk * 8 + srow) * 512 + gcol, Vs + chunk * 512);
        }
    }

    for (int kt = 0; kt <= qt; ++kt) {
        int cur = kt & 1;
        ushort* Ks = smem + cur * 8192;
        ushort* Vs = smem + cur * 8192 + 4096;
        __syncthreads();     // buf[cur] staged (vmcnt drained), prev compute done
        if (kt < qt) {       // prefetch next tile into the other buffer
            ushort* Kn = smem + (cur ^ 1) * 8192;
            ushort* Vn = Kn + 4096;
            #pragma unroll
            for (int c = 0; c < 2; ++c) {
                int chunk = w * 2 + c;
                gload16(Kp + (size_t)((kt + 1) * 64 + chunk * 8 + srow) * 64 + gcol,
                        Kn + chunk * 512);
                gload16(Vp + (size_t)(chunk * 8 + srow) * 512 + (kt + 1) * 64 + gcol,
                        Vn + chunk * 512);
            }
        }

        f32x4 sa[4] = {};
        #pragma unroll
        for (int n = 0; n < 4; ++n) {
            int rB = n * 16 + lc;
            bf16x8 b0 = *reinterpret_cast<const bf16x8*>(
                Ks + rB * 64 + ((sl ^ (rB & 7)) * 8));
            bf16x8 b1 = *reinterpret_cast<const bf16x8*>(
                Ks + rB * 64 + (((sl + 4) ^ (rB & 7)) * 8));
            sa[n] = __builtin_amdgcn_mfma_f32_16x16x32_bf16(qf0, b0, sa[n], 0, 0, 0);
            sa[n] = __builtin_amdgcn_mfma_f32_16x16x32_bf16(qf1, b1, sa[n], 0, 0, 0);
        }
        if (kt == qt) {
            #pragma unroll
            for (int n = 0; n < 4; ++n) {
                int col = kt * 64 + n * 16 + lc;
                #pragma unroll
                for (int r = 0; r < 4; ++r)
                    if (col > row_abs + r) sa[n][r] = -1e30f;
            }
        }
        float psum[4];
        #pragma unroll
        for (int r = 0; r < 4; ++r) {
            float vm = fmaxf(fmaxf(sa[0][r], sa[1][r]), fmaxf(sa[2][r], sa[3][r]));
            vm = fmaxf(vm, __shfl_xor(vm, 1));
            vm = fmaxf(vm, __shfl_xor(vm, 2));
            vm = fmaxf(vm, __shfl_xor(vm, 4));
            vm = fmaxf(vm, __shfl_xor(vm, 8));
            float mn = fmaxf(m_r[r], vm);
            float scl = __expf(m_r[r] - mn);
            m_r[r] = mn;
            l_r[r] *= scl;
            #pragma unroll
            for (int n = 0; n < 4; ++n) o[n][r] *= scl;
            psum[r] = 0.f;
        }
        ushort* Pw = Ps + w * 1024;
        #pragma unroll
        for (int n = 0; n < 4; ++n) {
            #pragma unroll
            for (int r = 0; r < 4; ++r) {
                float p = __expf(sa[n][r] - m_r[r]);
                psum[r] += p;
                int prow = sl * 4 + r;
                int pcol = n * 16 + lc;
                int pslot = pcol >> 3;
                Pw[prow * 64 + ((pslot ^ (prow & 7)) * 8) + (pcol & 7)] = f2b(p);
            }
        }
        #pragma unroll
        for (int r = 0; r < 4; ++r) {
            float s = psum[r];
            s += __shfl_xor(s, 1);
            s += __shfl_xor(s, 2);
            s += __shfl_xor(s, 4);
            s += __shfl_xor(s, 8);
            l_r[r] += s;
        }
        int arow = lc;
        bf16x8 pa0 = *reinterpret_cast<const bf16x8*>(
            Pw + arow * 64 + ((sl ^ (arow & 7)) * 8));
        bf16x8 pa1 = *reinterpret_cast<const bf16x8*>(
            Pw + arow * 64 + (((sl + 4) ^ (arow & 7)) * 8));
        #pragma unroll
        for (int n = 0; n < 4; ++n) {
            int rB = n * 16 + lc;
            bf16x8 v0 = *reinterpret_cast<const bf16x8*>(
                Vs + rB * 64 + ((sl ^ (rB & 7)) * 8));
            bf16x8 v1 = *reinterpret_cast<const bf16x8*>(
                Vs + rB * 64 + (((sl + 4) ^ (rB & 7)) * 8));
            o[n] = __builtin_amdgcn_mfma_f32_16x16x32_bf16(pa0, v0, o[n], 0, 0, 0);
            o[n] = __builtin_amdgcn_mfma_f32_16x16x32_bf16(pa1, v1, o[n], 0, 0, 0);
        }
    }

    int bb = bh >> 2, hh = bh & 3;
    #pragma unroll
    for (int r = 0; r < 4; ++r) {
        float inv = 1.f / l_r[r];
        int ss = qt * 64 + w * 16 + sl * 4 + r;
        #pragma unroll
        for (int n = 0; n < 4; ++n) {
            int dd = n * 16 + lc;
            pv[((size_t)bb * S_ + ss) * D_ + hh * HD_ + dd] = f2b(o[n][r] * inv);
        }
    }
}

// ===========================================================================
extern "C" void kernel_launch(void* const* d_in, const int* in_sizes, int n_in,
                              void* d_out, int out_size, void* d_ws, size_t ws_size,
                              hipStream_t stream)
{
    const int*   tok     = (const int*)  d_in[0];
    const float* ram     = (const float*)d_in[1];
    const float* proj_W  = (const float*)d_in[2];
    const float* proj_b  = (const float*)d_in[3];
    const float* pos_emb = (const float*)d_in[4];
    const float* sa_Wq   = (const float*)d_in[5];
    const float* sa_Wk   = (const float*)d_in[6];
    const float* sa_Wv   = (const float*)d_in[7];
    const float* sa_Wo   = (const float*)d_in[8];
    const float* sa_bq   = (const float*)d_in[9];
    const float* sa_bk   = (const float*)d_in[10];
    const float* sa_bv   = (const float*)d_in[11];
    const float* sa_bo   = (const float*)d_in[12];
    const float* ca_Wo   = (const float*)d_in[16];
    const float* ca_bv   = (const float*)d_in[19];
    const float* ca_bo   = (const float*)d_in[20];
    const float* ln1_s   = (const float*)d_in[21];
    const float* ln1_b   = (const float*)d_in[22];
    const float* ln3_s   = (const float*)d_in[25];
    const float* ln3_b   = (const float*)d_in[26];
    const float* ff_W1   = (const float*)d_in[27];
    const float* ff_b1   = (const float*)d_in[28];
    const float* ff_W2   = (const float*)d_in[29];
    const float* ff_b2   = (const float*)d_in[30];
    const float* out_W   = (const float*)d_in[31];
    const float* out_b   = (const float*)d_in[32];

    float* out = (float*)d_out;
    float* ws  = (float*)d_ws;

    // ws (must survive to logits): x | cc | xb | Wb
    float*  x   = ws;                            // BS_*D_ f32
    float*  cc  = ws + (size_t)BS_ * D_;         // L_*D_ f32
    ushort* xb  = (ushort*)(cc + L_ * D_);       // BS_*D_ bf16
    ushort* Wb  = xb + (size_t)BS_ * D_;         // V_*D_ bf16

    // d_out scratch (fully overwritten by the logits GEMM)
    ushort* sc_b  = (ushort*)out;                // 2,097,152
    ushort* h_b   = sc_b + 2097152;              // 1,048,576
    ushort* qkv3  = h_b + 1048576;               // 3,145,728 (q|k|vT)
    ushort* pv_b  = qkv3 + 3145728;              // 1,048,576
    ushort* ffh_b = pv_b + 1048576;              // 2,097,152
    ushort* pjWb  = ffh_b + 2097152;             // 131,072
    ushort* WqkvB = pjWb + 131072;               // 786,432  [L][768][256]
    ushort* WoB   = WqkvB + 786432;              // 262,144
    ushort* ff1B  = WoB + 262144;                // 524,288
    ushort* ff2B  = ff1B + 524288;               // 524,288
    float*  qkvb  = (float*)(ff2B + 524288);     // 4096 f32 (L*768 used)
    ushort* qb_b  = qkv3;
    ushort* kb_b  = qkv3 + 1048576;
    ushort* vT_b  = qkv3 + 2097152;

    prologue_kernel<<<14276, 256, 0, stream>>>(
        tok, ram, proj_W, sa_Wq, sa_Wk, sa_Wv, sa_Wo, ff_W1, ff_W2, out_W,
        ca_bv, ca_Wo, ca_bo, sa_bq, sa_bk, sa_bv,
        pjWb, WqkvB, WoB, ff1B, ff2B, Wb, cc, qkvb, sc_b);

    // x = scores @ proj_W + proj_b + pos_emb
    gemm_t<64, 64, 512, 256, FG_F32 | FG_POS><<<256, 256, 0, stream>>>(
        sc_b, pjWb, proj_b, nullptr, nullptr, pos_emb, x, nullptr);

    for (int l = 0; l < L_; ++l) {
        ln_bf16_kernel<<<1024, 256, 0, stream>>>(x, ln1_s + l * D_, ln1_b + l * D_, h_b);
        gemm_t<64, 64, 256, 768, FG_QKV><<<768, 256, 0, stream>>>(
            h_b, WqkvB + (size_t)l * 196608, qkvb + l * 768,
            nullptr, nullptr, nullptr, nullptr, qkv3);
        attn_kernel<<<dim3(8, 32), 256, 0, stream>>>(qb_b, kb_b, vT_b, pv_b);
        // x = x + pv @ Wo + bo + cc[l]
        gemm_t<64, 64, 256, 256, FG_F32><<<256, 256, 0, stream>>>(
            pv_b, WoB + (size_t)l * 65536, sa_bo + l * D_,
            cc + l * D_, x, nullptr, x, nullptr);
        ln_bf16_kernel<<<1024, 256, 0, stream>>>(x, ln3_s + l * D_, ln3_b + l * D_, h_b);
        gemm_t<64, 64, 256, 512, FG_BF16 | FG_RELU><<<512, 256, 0, stream>>>(
            h_b, ff1B + (size_t)l * 131072, ff_b1 + l * FF_,
            nullptr, nullptr, nullptr, nullptr, ffh_b);
        if (l < L_ - 1) {
            gemm_t<64, 64, 512, 256, FG_F32><<<256, 256, 0, stream>>>(
                ffh_b, ff2B + (size_t)l * 131072, ff_b2 + l * D_,
                nullptr, x, nullptr, x, nullptr);
        } else {
            // last layer: emit x as bf16 directly for the logits GEMM
            gemm_t<64, 64, 512, 256, FG_BF16><<<256, 256, 0, stream>>>(
                ffh_b, ff2B + (size_t)l * 131072, ff_b2 + l * D_,
                nullptr, x, nullptr, nullptr, xb);
        }
    }

    // logits = xb @ Wb^T + out_b  (overwrites all of d_out)
    gemm_t<128, 128, 256, 32000, FG_F32 | FG_NT><<<8000, 256, 0, stream>>>(
        xb, Wb, out_b, nullptr, nullptr, nullptr, out, nullptr);
}

// Round 10
// 389.244 us; speedup vs baseline: 7.9287x; 1.0277x over previous
//
#include <hip/hip_runtime.h>

#define B_   8
#define S_   512
#define V_   32000
#define CTX_ 8
#define NC_  512
#define D_   256
#define NH_  4
#define L_   4
#define FF_  512
#define HD_  64
#define BS_  4096   // B_*S_

#define FG_F32   1
#define FG_BF16  2
#define FG_RELU  4
#define FG_POS   8
#define FG_NT    16
#define FG_QKV   32

typedef __attribute__((ext_vector_type(8))) short bf16x8;
typedef __attribute__((ext_vector_type(4))) float f32x4;

__device__ inline void gload16(const void* g, void* lds) {
    __builtin_amdgcn_global_load_lds(
        (const __attribute__((address_space(1))) void*)g,
        (__attribute__((address_space(3))) void*)lds, 16, 0, 0);
}

__device__ inline ushort f2b(float f) {   // f32 -> bf16 RNE
    union { float f; unsigned u; } v; v.f = f;
    unsigned u = v.u;
    unsigned r = u + 0x7fffu + ((u >> 16) & 1u);
    return (ushort)(r >> 16);
}

// ---------------------------------------------------------------------------
// Prologue (ONE launch): flat job grid.
// ---------------------------------------------------------------------------
__global__ __launch_bounds__(256) void prologue_kernel(
    const int* __restrict__ tok, const float* __restrict__ ram,
    const float* __restrict__ proj_W, const float* __restrict__ Wq,
    const float* __restrict__ Wk, const float* __restrict__ Wv,
    const float* __restrict__ Wo, const float* __restrict__ W1,
    const float* __restrict__ W2, const float* __restrict__ outW,
    const float* __restrict__ ca_bv, const float* __restrict__ ca_Wo,
    const float* __restrict__ ca_bo, const float* __restrict__ bq,
    const float* __restrict__ bk, const float* __restrict__ bv,
    ushort* __restrict__ pjWb, ushort* __restrict__ WqkvB,
    ushort* __restrict__ WoB, ushort* __restrict__ ff1B,
    ushort* __restrict__ ff2B, ushort* __restrict__ Wb,
    float* __restrict__ cc, float* __restrict__ qkvb,
    ushort* __restrict__ scores)
{
    __shared__ float tile[32 * 33];
    int id = blockIdx.x;
    int t = threadIdx.x;
    if (id < 10176) {
        const float* src; ushort* dst; int K, N, lt;
        if (id < 128)       { src = proj_W; dst = pjWb; K = 512; N = 256; lt = id; }
        else if (id < 896)  { lt = id - 128; int z = lt >> 6; lt &= 63;
                              int which = z / L_, l = z % L_;
                              src = (which == 0 ? Wq : which == 1 ? Wk : Wv) + (size_t)l * 65536;
                              dst = WqkvB + ((size_t)l * 768 + which * 256) * 256;
                              K = 256; N = 256; }
        else if (id < 1152) { lt = id - 896; int l = lt >> 6; lt &= 63;
                              src = Wo + (size_t)l * 65536; dst = WoB + (size_t)l * 65536;
                              K = 256; N = 256; }
        else if (id < 1664) { lt = id - 1152; int l = lt >> 7; lt &= 127;
                              src = W1 + (size_t)l * 131072; dst = ff1B + (size_t)l * 131072;
                              K = 256; N = 512; }
        else if (id < 2176) { lt = id - 1664; int l = lt >> 7; lt &= 127;
                              src = W2 + (size_t)l * 131072; dst = ff2B + (size_t)l * 131072;
                              K = 512; N = 256; }
        else                { lt = id - 2176; src = outW; dst = Wb; K = 256; N = 32000; }
        int ntc = N >> 5;
        int n0 = (lt % ntc) * 32, k0 = (lt / ntc) * 32;
        int tx = t & 31, ty = t >> 5;
        for (int i = ty; i < 32; i += 8)
            tile[i * 33 + tx] = src[(size_t)(k0 + i) * N + n0 + tx];
        __syncthreads();
        for (int i = ty; i < 32; i += 8)
            dst[(size_t)(n0 + i) * K + k0 + tx] = f2b(tile[tx * 33 + i]);
    } else if (id < 10180) {
        int l = id - 10176;
        const float* w = ca_Wo + (size_t)l * D_ * D_;
        const float* b = ca_bv + l * D_;
        float acc = 0.f;
        for (int d = 0; d < D_; ++d) acc += b[d] * w[(size_t)d * D_ + t];
        cc[l * D_ + t] = acc + ca_bo[l * D_ + t];
        for (int u = t; u < 768; u += 256) {
            int which = u >> 8, c = u & 255;
            const float* src = which == 0 ? bq : which == 1 ? bk : bv;
            qkvb[l * 768 + u] = src[l * 256 + c];
        }
    } else {
        int bs = id - 10180;
        int b = bs >> 9, s = bs & 511;
        float a0 = 0.f, a1 = 0.f;
        #pragma unroll
        for (int c = 0; c < CTX_; ++c) {
            int pos = s + c - (CTX_ - 1);
            int tk = (pos < 0) ? 0 : tok[b * S_ + pos];
            const float* row = ram + (size_t)tk * NC_;
            a0 += row[t];
            a1 += row[t + 256];
        }
        scores[(size_t)bs * NC_ + t]       = f2b(a0 * 0.125f);
        scores[(size_t)bs * NC_ + t + 256] = f2b(a1 * 0.125f);
    }
}

// ---------------------------------------------------------------------------
// Row-GEMM with fused LayerNorm epilogue.  BM=16, BN=TN=256, grid 256.
// C_row = A[16][K] @ Bt[256][K]^T + bias (+extra +resid +pos); writes:
//   Xout[row][256] = v (f32)   and   Hout[row][256] = LN(v)*lnS+lnB (bf16)
// 4 waves, wave w owns cols w*64..w*64+63 of all 16 rows.
// ---------------------------------------------------------------------------
template<int K, int FLAGS>
__global__ __launch_bounds__(256) void gemm_row(
    const ushort* __restrict__ A, const ushort* __restrict__ Bt,
    const float* __restrict__ bias, const float* __restrict__ extra,
    const float* __restrict__ resid, const float* __restrict__ pos,
    const float* __restrict__ lnS, const float* __restrict__ lnB,
    float* __restrict__ Xout, ushort* __restrict__ Hout)
{
    __shared__ ushort As[16 * 64];       // 2 KB
    __shared__ ushort Bs[256 * 64];      // 32 KB
    __shared__ float red[2][4][16];      // [sum|sq][wave][row]
    int mt = blockIdx.x;
    int row0 = mt * 16;
    int t = threadIdx.x, w = t >> 6, lane = t & 63;
    int srow = lane >> 3, slot = lane & 7;
    int gcol = (slot ^ srow) * 8;
    int sl = lane >> 4, lc = lane & 15;
    int rA = lane & 15;                  // A row (0..15)

    f32x4 acc[4] = {};

    #pragma unroll
    for (int k0 = 0; k0 < K; k0 += 64) {
        if (w < 2)
            gload16(A + (size_t)(row0 + w * 8 + srow) * K + k0 + gcol, As + w * 512);
        #pragma unroll
        for (int c = 0; c < 8; ++c) {
            int chunk = w * 8 + c;
            gload16(Bt + (size_t)(chunk * 8 + srow) * K + k0 + gcol, Bs + chunk * 512);
        }
        __syncthreads();
        #pragma unroll
        for (int kk = 0; kk < 2; ++kk) {
            bf16x8 a = *reinterpret_cast<const bf16x8*>(
                As + rA * 64 + (((sl + kk * 4) ^ (rA & 7)) * 8));
            #pragma unroll
            for (int n = 0; n < 4; ++n) {
                int rr = w * 64 + n * 16 + lc;   // B row = output col... frag row base
                rr = w * 64 + (lane & 15) + n * 16;
                bf16x8 b = *reinterpret_cast<const bf16x8*>(
                    Bs + rr * 64 + (((sl + kk * 4) ^ (rr & 7)) * 8));
                acc[n] = __builtin_amdgcn_mfma_f32_16x16x32_bf16(a, b, acc[n], 0, 0, 0);
            }
        }
        __syncthreads();
    }

    // epilogue: v = acc + bias (+pos) (+extra) (+resid)
    float v[4][4];
    float psum[4] = {}, psq[4] = {};
    #pragma unroll
    for (int n = 0; n < 4; ++n) {
        int col = w * 64 + n * 16 + lc;
        float bn = bias[col];
        float en = extra ? extra[col] : 0.f;
        #pragma unroll
        for (int r = 0; r < 4; ++r) {
            int row = row0 + sl * 4 + r;
            float x = acc[n][r] + bn;
            if constexpr (FLAGS & FG_POS) x += pos[(size_t)(row & 511) * D_ + col];
            x += en;
            if (resid) x += resid[(size_t)row * D_ + col];
            v[n][r] = x;
            psum[r] += x;
            psq[r] += x * x;
        }
    }
    // reduce over the 16 lanes sharing sl (cols within wave)
    #pragma unroll
    for (int r = 0; r < 4; ++r) {
        #pragma unroll
        for (int o = 8; o > 0; o >>= 1) {
            psum[r] += __shfl_xor(psum[r], o);
            psq[r]  += __shfl_xor(psq[r], o);
        }
    }
    if (lc == 0) {
        #pragma unroll
        for (int r = 0; r < 4; ++r) {
            red[0][w][sl * 4 + r] = psum[r];
            red[1][w][sl * 4 + r] = psq[r];
        }
    }
    __syncthreads();
    #pragma unroll
    for (int r = 0; r < 4; ++r) {
        int rl = sl * 4 + r;
        float s  = red[0][0][rl] + red[0][1][rl] + red[0][2][rl] + red[0][3][rl];
        float s2 = red[1][0][rl] + red[1][1][rl] + red[1][2][rl] + red[1][3][rl];
        float mean = s * (1.f / D_);
        float var = s2 * (1.f / D_) - mean * mean;
        float rstd = rsqrtf(var + 1e-5f);
        int row = row0 + rl;
        #pragma unroll
        for (int n = 0; n < 4; ++n) {
            int col = w * 64 + n * 16 + lc;
            float x = v[n][r];
            Xout[(size_t)row * D_ + col] = x;
            Hout[(size_t)row * D_ + col] =
                f2b((x - mean) * rstd * lnS[col] + lnB[col]);
        }
    }
}

// ---------------------------------------------------------------------------
// Templated bf16 MFMA GEMM.  A[4096][K] bf16, Bt[TN][K] bf16.
// 4 waves (2x2).  BK=64.  LDS XOR-swizzled (T2, both-sides rule #21).
// FG_NT: epilogue stages C through LDS -> coalesced f32x4 nontemporal stores.
// ---------------------------------------------------------------------------
template<int BM, int BN, int K, int TN, int FLAGS>
__global__ __launch_bounds__(256) void gemm_t(
    const ushort* __restrict__ A, const ushort* __restrict__ Bt,
    const float* __restrict__ bias, const float* __restrict__ extra,
    const float* __restrict__ resid, const float* __restrict__ pos,
    float* __restrict__ Cf, ushort* __restrict__ Cb)
{
    constexpr int WM = BM / 32;
    constexpr int WN = BN / 32;
    constexpr int MT = 4096 / BM;
    constexpr int NWG = MT * (TN / BN);
    __shared__ ushort smem[(BM + BN) * 64];
    ushort* As = smem;
    ushort* Bs = smem + BM * 64;
    int bid = blockIdx.x;
    int swz = bid;
    if constexpr ((NWG & 7) == 0) {
        constexpr int cpx = NWG >> 3;
        swz = (bid & 7) * cpx + (bid >> 3);
    }
    int mt = swz % MT, nt = swz / MT;
    int row0 = mt * BM, col0 = nt * BN;
    int t = threadIdx.x, w = t >> 6, lane = t & 63;
    int wr = w >> 1, wc = w & 1;
    int srow = lane >> 3, slot = lane & 7;
    int gcol = (slot ^ srow) * 8;          // inverse-swizzled global col

    f32x4 acc[WM][WN] = {};
    int sl = lane >> 4;
    int rA0 = wr * (BM / 2) + (lane & 15);
    int rB0 = wc * (BN / 2) + (lane & 15);

    #pragma unroll
    for (int k0 = 0; k0 < K; k0 += 64) {
        #pragma unroll
        for (int c = 0; c < BM / 32; ++c) {
            int chunk = w * (BM / 32) + c;
            gload16(A + (size_t)(row0 + chunk * 8 + srow) * K + k0 + gcol,
                    As + chunk * 512);
        }
        #pragma unroll
        for (int c = 0; c < BN / 32; ++c) {
            int chunk = w * (BN / 32) + c;
            gload16(Bt + (size_t)(col0 + chunk * 8 + srow) * K + k0 + gcol,
                    Bs + chunk * 512);
        }
        __syncthreads();
        #pragma unroll
        for (int kk = 0; kk < 2; ++kk) {
            bf16x8 a[WM], b[WN];
            #pragma unroll
            for (int m = 0; m < WM; ++m) {
                int rr = rA0 + m * 16;
                a[m] = *reinterpret_cast<const bf16x8*>(
                    As + rr * 64 + (((sl + kk * 4) ^ (rr & 7)) * 8));
            }
            #pragma unroll
            for (int n = 0; n < WN; ++n) {
                int rr = rB0 + n * 16;
                b[n] = *reinterpret_cast<const bf16x8*>(
                    Bs + rr * 64 + (((sl + kk * 4) ^ (rr & 7)) * 8));
            }
            #pragma unroll
            for (int m = 0; m < WM; ++m)
                #pragma unroll
                for (int n = 0; n < WN; ++n)
                    acc[m][n] = __builtin_amdgcn_mfma_f32_16x16x32_bf16(
                        a[m], b[n], acc[m][n], 0, 0, 0);
        }
        __syncthreads();
    }

    int lr = (lane >> 4) * 4;
    int lc = lane & 15;

    if constexpr (FLAGS & FG_NT) {
        // C half-tile through LDS -> coalesced f32x4 nontemporal stores.
        float* Ct = reinterpret_cast<float*>(smem);   // (BM/2)*BN f32 == smem size
        #pragma unroll
        for (int p = 0; p < 2; ++p) {
            __syncthreads();
            if (wr == p) {
                #pragma unroll
                for (int n = 0; n < WN; ++n) {
                    int colL = wc * (BN / 2) + n * 16 + lc;
                    float bn = bias[col0 + colL];
                    #pragma unroll
                    for (int m = 0; m < WM; ++m)
                        #pragma unroll
                        for (int r = 0; r < 4; ++r)
                            Ct[(m * 16 + lr + r) * BN + colL] = acc[m][n][r] + bn;
                }
            }
            __syncthreads();
            constexpr int NV4 = (BM / 2) * (BN / 4);
            #pragma unroll
            for (int j = 0; j < NV4 / 256; ++j) {
                int idx = t + j * 256;
                int rl = idx / (BN / 4);
                int c4 = idx % (BN / 4);
                f32x4 v4 = reinterpret_cast<const f32x4*>(Ct)[idx];
                __builtin_nontemporal_store(v4,
                    reinterpret_cast<f32x4*>(
                        &Cf[(size_t)(row0 + p * (BM / 2) + rl) * TN + col0 + c4 * 4]));
            }
        }
        return;
    }

    #pragma unroll
    for (int n = 0; n < WN; ++n) {
        int col = col0 + wc * (BN / 2) + n * 16 + lc;
        float bn = bias ? bias[col] : 0.f;
        float en = extra ? extra[col] : 0.f;
        #pragma unroll
        for (int m = 0; m < WM; ++m) {
            int rbase = row0 + wr * (BM / 2) + m * 16 + lr;
            #pragma unroll
            for (int r = 0; r < 4; ++r) {
                int row = rbase + r;
                float v = acc[m][n][r] + bn;
                if constexpr (FLAGS & FG_QKV) {
                    int which = col >> 8;
                    int c2 = col & 255;
                    int hh = c2 >> 6, dd = c2 & 63;
                    int bb = row >> 9, ss = row & 511;
                    if (which == 0) {
                        Cb[((((size_t)bb * NH_ + hh) * S_ + ss) << 6) + dd] =
                            f2b(v * 0.125f);
                    } else if (which == 1) {
                        (Cb + 1048576)[((((size_t)bb * NH_ + hh) * S_ + ss) << 6) + dd] =
                            f2b(v);
                    } else {
                        (Cb + 2097152)[((((size_t)bb * NH_ + hh) * HD_ + dd) << 9) + ss] =
                            f2b(v);
                    }
                } else {
                    if constexpr (FLAGS & FG_POS) v += pos[(size_t)(row & 511) * TN + col];
                    if (extra) v += en;
                    if (resid) v += resid[(size_t)row * TN + col];
                    if constexpr (FLAGS & FG_RELU) v = fmaxf(v, 0.f);
                    if constexpr (FLAGS & FG_BF16)
                        Cb[(size_t)row * TN + col] = f2b(v);
                    if constexpr (FLAGS & FG_F32)
                        Cf[(size_t)row * TN + col] = v;
                }
            }
        }
    }
}

// ---------------------------------------------------------------------------
// Fused flash attention, K/V double-buffered: one block per (q-tile, bh).
// ---------------------------------------------------------------------------
__global__ __launch_bounds__(256) void attn_kernel(
    const ushort* __restrict__ q, const ushort* __restrict__ k,
    const ushort* __restrict__ vT, ushort* __restrict__ pv)
{
    int qt = blockIdx.x, bh = blockIdx.y;
    __shared__ ushort smem[20480];       // 2x(Ks 4096 + Vs 4096) + Ps 4096
    ushort* Ps = smem + 16384;
    int t = threadIdx.x, w = t >> 6, lane = t & 63;
    int srow = lane >> 3, slot = lane & 7;
    int gcol = (slot ^ srow) * 8;
    int sl = lane >> 4, lc = lane & 15;

    const ushort* Qp = q + ((size_t)bh * S_ + qt * 64) * HD_;
    const ushort* Kp = k + (size_t)bh * S_ * HD_;
    const ushort* Vp = vT + (size_t)bh * HD_ * S_;

    int qrow = w * 16 + lc;
    bf16x8 qf0 = *reinterpret_cast<const bf16x8*>(Qp + qrow * 64 + sl * 8);
    bf16x8 qf1 = *reinterpret_cast<const bf16x8*>(Qp + qrow * 64 + sl * 8 + 32);

    f32x4 o[4] = {};
    float m_r[4], l_r[4];
    #pragma unroll
    for (int r = 0; r < 4; ++r) { m_r[r] = -1e30f; l_r[r] = 0.f; }
    int row_abs = qt * 64 + w * 16 + sl * 4;

    {
        ushort* Ks = smem;
        ushort* Vs = smem + 4096;
        #pragma unroll
        for (int c = 0; c < 2; ++c) {
            int chunk = w * 2 + c;
            gload16(Kp + (size_t)(chunk * 8 + srow) * 64 + gcol, Ks + chunk * 512);
            gload16(Vp + (size_t)(chunk * 8 + srow) * 512 + gcol, Vs + chunk * 512);
        }
    }

    for (int kt = 0; kt <= qt; ++kt) {
        int cur = kt & 1;
        ushort* Ks = smem + cur * 8192;
        ushort* Vs = smem + cur * 8192 + 4096;
        __syncthreads();
        if (kt < qt) {
            ushort* Kn = smem + (cur ^ 1) * 8192;
            ushort* Vn = Kn + 4096;
            #pragma unroll
            for (int c = 0; c < 2; ++c) {
                int chunk = w * 2 + c;
                gload16(Kp + (size_t)((kt + 1) * 64 + chunk * 8 + srow) * 64 + gcol,
                        Kn + chunk * 512);
                gload16(Vp + (size_t)(chunk * 8 + srow) * 512 + (kt + 1) * 64 + gcol,
                        Vn + chunk * 512);
            }
        }

        f32x4 sa[4] = {};
        #pragma unroll
        for (int n = 0; n < 4; ++n) {
            int rB = n * 16 + lc;
            bf16x8 b0 = *reinterpret_cast<const bf16x8*>(
                Ks + rB * 64 + ((sl ^ (rB & 7)) * 8));
            bf16x8 b1 = *reinterpret_cast<const bf16x8*>(
                Ks + rB * 64 + (((sl + 4) ^ (rB & 7)) * 8));
            sa[n] = __builtin_amdgcn_mfma_f32_16x16x32_bf16(qf0, b0, sa[n], 0, 0, 0);
            sa[n] = __builtin_amdgcn_mfma_f32_16x16x32_bf16(qf1, b1, sa[n], 0, 0, 0);
        }
        if (kt == qt) {
            #pragma unroll
            for (int n = 0; n < 4; ++n) {
                int col = kt * 64 + n * 16 + lc;
                #pragma unroll
                for (int r = 0; r < 4; ++r)
                    if (col > row_abs + r) sa[n][r] = -1e30f;
            }
        }
        float psum[4];
        #pragma unroll
        for (int r = 0; r < 4; ++r) {
            float vm = fmaxf(fmaxf(sa[0][r], sa[1][r]), fmaxf(sa[2][r], sa[3][r]));
            vm = fmaxf(vm, __shfl_xor(vm, 1));
            vm = fmaxf(vm, __shfl_xor(vm, 2));
            vm = fmaxf(vm, __shfl_xor(vm, 4));
            vm = fmaxf(vm, __shfl_xor(vm, 8));
            float mn = fmaxf(m_r[r], vm);
            float scl = __expf(m_r[r] - mn);
            m_r[r] = mn;
            l_r[r] *= scl;
            #pragma unroll
            for (int n = 0; n < 4; ++n) o[n][r] *= scl;
            psum[r] = 0.f;
        }
        ushort* Pw = Ps + w * 1024;
        #pragma unroll
        for (int n = 0; n < 4; ++n) {
            #pragma unroll
            for (int r = 0; r < 4; ++r) {
                float p = __expf(sa[n][r] - m_r[r]);
                psum[r] += p;
                int prow = sl * 4 + r;
                int pcol = n * 16 + lc;
                int pslot = pcol >> 3;
                Pw[prow * 64 + ((pslot ^ (prow & 7)) * 8) + (pcol & 7)] = f2b(p);
            }
        }
        #pragma unroll
        for (int r = 0; r < 4; ++r) {
            float s = psum[r];
            s += __shfl_xor(s, 1);
            s += __shfl_xor(s, 2);
            s += __shfl_xor(s, 4);
            s += __shfl_xor(s, 8);
            l_r[r] += s;
        }
        int arow = lc;
        bf16x8 pa0 = *reinterpret_cast<const bf16x8*>(
            Pw + arow * 64 + ((sl ^ (arow & 7)) * 8));
        bf16x8 pa1 = *reinterpret_cast<const bf16x8*>(
            Pw + arow * 64 + (((sl + 4) ^ (arow & 7)) * 8));
        #pragma unroll
        for (int n = 0; n < 4; ++n) {
            int rB = n * 16 + lc;
            bf16x8 v0 = *reinterpret_cast<const bf16x8*>(
                Vs + rB * 64 + ((sl ^ (rB & 7)) * 8));
            bf16x8 v1 = *reinterpret_cast<const bf16x8*>(
                Vs + rB * 64 + (((sl + 4) ^ (rB & 7)) * 8));
            o[n] = __builtin_amdgcn_mfma_f32_16x16x32_bf16(pa0, v0, o[n], 0, 0, 0);
            o[n] = __builtin_amdgcn_mfma_f32_16x16x32_bf16(pa1, v1, o[n], 0, 0, 0);
        }
    }

    int bb = bh >> 2, hh = bh & 3;
    #pragma unroll
    for (int r = 0; r < 4; ++r) {
        float inv = 1.f / l_r[r];
        int ss = qt * 64 + w * 16 + sl * 4 + r;
        #pragma unroll
        for (int n = 0; n < 4; ++n) {
            int dd = n * 16 + lc;
            pv[((size_t)bb * S_ + ss) * D_ + hh * HD_ + dd] = f2b(o[n][r] * inv);
        }
    }
}

// ===========================================================================
extern "C" void kernel_launch(void* const* d_in, const int* in_sizes, int n_in,
                              void* d_out, int out_size, void* d_ws, size_t ws_size,
                              hipStream_t stream)
{
    const int*   tok     = (const int*)  d_in[0];
    const float* ram     = (const float*)d_in[1];
    const float* proj_W  = (const float*)d_in[2];
    const float* proj_b  = (const float*)d_in[3];
    const float* pos_emb = (const float*)d_in[4];
    const float* sa_Wq   = (const float*)d_in[5];
    const float* sa_Wk   = (const float*)d_in[6];
    const float* sa_Wv   = (const float*)d_in[7];
    const float* sa_Wo   = (const float*)d_in[8];
    const float* sa_bq   = (const float*)d_in[9];
    const float* sa_bk   = (const float*)d_in[10];
    const float* sa_bv   = (const float*)d_in[11];
    const float* sa_bo   = (const float*)d_in[12];
    const float* ca_Wo   = (const float*)d_in[16];
    const float* ca_bv   = (const float*)d_in[19];
    const float* ca_bo   = (const float*)d_in[20];
    const float* ln1_s   = (const float*)d_in[21];
    const float* ln1_b   = (const float*)d_in[22];
    const float* ln3_s   = (const float*)d_in[25];
    const float* ln3_b   = (const float*)d_in[26];
    const float* ff_W1   = (const float*)d_in[27];
    const float* ff_b1   = (const float*)d_in[28];
    const float* ff_W2   = (const float*)d_in[29];
    const float* ff_b2   = (const float*)d_in[30];
    const float* out_W   = (const float*)d_in[31];
    const float* out_b   = (const float*)d_in[32];

    float* out = (float*)d_out;
    float* ws  = (float*)d_ws;

    // ws (must survive to logits): x | cc | xb | Wb
    float*  x   = ws;                            // BS_*D_ f32
    float*  cc  = ws + (size_t)BS_ * D_;         // L_*D_ f32
    ushort* xb  = (ushort*)(cc + L_ * D_);       // BS_*D_ bf16
    ushort* Wb  = xb + (size_t)BS_ * D_;         // V_*D_ bf16

    // d_out scratch (fully overwritten by the logits GEMM)
    ushort* sc_b  = (ushort*)out;                // 2,097,152
    ushort* h_b   = sc_b + 2097152;              // 1,048,576
    ushort* qkv3  = h_b + 1048576;               // 3,145,728 (q|k|vT)
    ushort* pv_b  = qkv3 + 3145728;              // 1,048,576
    ushort* ffh_b = pv_b + 1048576;              // 2,097,152
    ushort* pjWb  = ffh_b + 2097152;             // 131,072
    ushort* WqkvB = pjWb + 131072;               // 786,432  [L][768][256]
    ushort* WoB   = WqkvB + 786432;              // 262,144
    ushort* ff1B  = WoB + 262144;                // 524,288
    ushort* ff2B  = ff1B + 524288;               // 524,288
    float*  qkvb  = (float*)(ff2B + 524288);     // 4096 f32 (L*768 used)
    ushort* qb_b  = qkv3;
    ushort* kb_b  = qkv3 + 1048576;
    ushort* vT_b  = qkv3 + 2097152;

    prologue_kernel<<<14276, 256, 0, stream>>>(
        tok, ram, proj_W, sa_Wq, sa_Wk, sa_Wv, sa_Wo, ff_W1, ff_W2, out_W,
        ca_bv, ca_Wo, ca_bo, sa_bq, sa_bk, sa_bv,
        pjWb, WqkvB, WoB, ff1B, ff2B, Wb, cc, qkvb, sc_b);

    // x = scores @ proj_W + proj_b + pos_emb; h_b = ln1_0(x)   (fused)
    gemm_row<512, FG_POS><<<256, 256, 0, stream>>>(
        sc_b, pjWb, proj_b, nullptr, nullptr, pos_emb,
        ln1_s, ln1_b, x, h_b);

    for (int l = 0; l < L_; ++l) {
        gemm_t<64, 64, 256, 768, FG_QKV><<<768, 256, 0, stream>>>(
            h_b, WqkvB + (size_t)l * 196608, qkvb + l * 768,
            nullptr, nullptr, nullptr, nullptr, qkv3);
        attn_kernel<<<dim3(8, 32), 256, 0, stream>>>(qb_b, kb_b, vT_b, pv_b);
        // x = x + pv @ Wo + bo + cc[l]; h_b = ln3(x)   (fused)
        gemm_row<256, 0><<<256, 256, 0, stream>>>(
            pv_b, WoB + (size_t)l * 65536, sa_bo + l * D_,
            cc + l * D_, x, nullptr, ln3_s + l * D_, ln3_b + l * D_, x, h_b);
        gemm_t<64, 64, 256, 512, FG_BF16 | FG_RELU><<<512, 256, 0, stream>>>(
            h_b, ff1B + (size_t)l * 131072, ff_b1 + l * FF_,
            nullptr, nullptr, nullptr, nullptr, ffh_b);
        if (l < L_ - 1) {
            // x = x + ffh @ W2 + b2; h_b = ln1_{l+1}(x)   (fused)
            gemm_row<512, 0><<<256, 256, 0, stream>>>(
                ffh_b, ff2B + (size_t)l * 131072, ff_b2 + l * D_,
                nullptr, x, nullptr, ln1_s + (l + 1) * D_, ln1_b + (l + 1) * D_,
                x, h_b);
        } else {
            // last layer: emit x as bf16 directly for the logits GEMM
            gemm_t<64, 64, 512, 256, FG_BF16><<<256, 256, 0, stream>>>(
                ffh_b, ff2B + (size_t)l * 131072, ff_b2 + l * D_,
                nullptr, x, nullptr, nullptr, xb);
        }
    }

    // logits = xb @ Wb^T + out_b  (overwrites all of d_out)
    gemm_t<128, 128, 256, 32000, FG_F32 | FG_NT><<<8000, 256, 0, stream>>>(
        xb, Wb, out_b, nullptr, nullptr, nullptr, out, nullptr);
}

// Round 11
// 380.082 us; speedup vs baseline: 8.1198x; 1.0241x over previous
//
#include <hip/hip_runtime.h>

#define B_   8
#define S_   512
#define V_   32000
#define CTX_ 8
#define NC_  512
#define D_   256
#define NH_  4
#define L_   4
#define FF_  512
#define HD_  64
#define BS_  4096   // B_*S_

#define FG_F32   1
#define FG_BF16  2
#define FG_RELU  4
#define FG_POS   8
#define FG_NT    16
#define FG_QKV   32

typedef __attribute__((ext_vector_type(8))) short bf16x8;
typedef __attribute__((ext_vector_type(4))) float f32x4;

__device__ inline void gload16(const void* g, void* lds) {
    __builtin_amdgcn_global_load_lds(
        (const __attribute__((address_space(1))) void*)g,
        (__attribute__((address_space(3))) void*)lds, 16, 0, 0);
}

__device__ inline ushort f2b(float f) {   // f32 -> bf16 RNE
    union { float f; unsigned u; } v; v.f = f;
    unsigned u = v.u;
    unsigned r = u + 0x7fffu + ((u >> 16) & 1u);
    return (ushort)(r >> 16);
}

// ---------------------------------------------------------------------------
// Prologue (ONE launch): flat job grid.
// ---------------------------------------------------------------------------
__global__ __launch_bounds__(256) void prologue_kernel(
    const int* __restrict__ tok, const float* __restrict__ ram,
    const float* __restrict__ proj_W, const float* __restrict__ Wq,
    const float* __restrict__ Wk, const float* __restrict__ Wv,
    const float* __restrict__ Wo, const float* __restrict__ W1,
    const float* __restrict__ W2, const float* __restrict__ outW,
    const float* __restrict__ ca_bv, const float* __restrict__ ca_Wo,
    const float* __restrict__ ca_bo, const float* __restrict__ bq,
    const float* __restrict__ bk, const float* __restrict__ bv,
    ushort* __restrict__ pjWb, ushort* __restrict__ WqkvB,
    ushort* __restrict__ WoB, ushort* __restrict__ ff1B,
    ushort* __restrict__ ff2B, ushort* __restrict__ Wb,
    float* __restrict__ cc, float* __restrict__ qkvb,
    ushort* __restrict__ scores)
{
    __shared__ float tile[32 * 33];
    int id = blockIdx.x;
    int t = threadIdx.x;
    if (id < 10176) {
        const float* src; ushort* dst; int K, N, lt;
        if (id < 128)       { src = proj_W; dst = pjWb; K = 512; N = 256; lt = id; }
        else if (id < 896)  { lt = id - 128; int z = lt >> 6; lt &= 63;
                              int which = z / L_, l = z % L_;
                              src = (which == 0 ? Wq : which == 1 ? Wk : Wv) + (size_t)l * 65536;
                              dst = WqkvB + ((size_t)l * 768 + which * 256) * 256;
                              K = 256; N = 256; }
        else if (id < 1152) { lt = id - 896; int l = lt >> 6; lt &= 63;
                              src = Wo + (size_t)l * 65536; dst = WoB + (size_t)l * 65536;
                              K = 256; N = 256; }
        else if (id < 1664) { lt = id - 1152; int l = lt >> 7; lt &= 127;
                              src = W1 + (size_t)l * 131072; dst = ff1B + (size_t)l * 131072;
                              K = 256; N = 512; }
        else if (id < 2176) { lt = id - 1664; int l = lt >> 7; lt &= 127;
                              src = W2 + (size_t)l * 131072; dst = ff2B + (size_t)l * 131072;
                              K = 512; N = 256; }
        else                { lt = id - 2176; src = outW; dst = Wb; K = 256; N = 32000; }
        int ntc = N >> 5;
        int n0 = (lt % ntc) * 32, k0 = (lt / ntc) * 32;
        int tx = t & 31, ty = t >> 5;
        for (int i = ty; i < 32; i += 8)
            tile[i * 33 + tx] = src[(size_t)(k0 + i) * N + n0 + tx];
        __syncthreads();
        for (int i = ty; i < 32; i += 8)
            dst[(size_t)(n0 + i) * K + k0 + tx] = f2b(tile[tx * 33 + i]);
    } else if (id < 10180) {
        int l = id - 10176;
        const float* w = ca_Wo + (size_t)l * D_ * D_;
        const float* b = ca_bv + l * D_;
        float acc = 0.f;
        for (int d = 0; d < D_; ++d) acc += b[d] * w[(size_t)d * D_ + t];
        cc[l * D_ + t] = acc + ca_bo[l * D_ + t];
        for (int u = t; u < 768; u += 256) {
            int which = u >> 8, c = u & 255;
            const float* src = which == 0 ? bq : which == 1 ? bk : bv;
            qkvb[l * 768 + u] = src[l * 256 + c];
        }
    } else {
        int bs = id - 10180;
        int b = bs >> 9, s = bs & 511;
        float a0 = 0.f, a1 = 0.f;
        #pragma unroll
        for (int c = 0; c < CTX_; ++c) {
            int pos = s + c - (CTX_ - 1);
            int tk = (pos < 0) ? 0 : tok[b * S_ + pos];
            const float* row = ram + (size_t)tk * NC_;
            a0 += row[t];
            a1 += row[t + 256];
        }
        scores[(size_t)bs * NC_ + t]       = f2b(a0 * 0.125f);
        scores[(size_t)bs * NC_ + t + 256] = f2b(a1 * 0.125f);
    }
}

// ---------------------------------------------------------------------------
// Row-GEMM with fused LayerNorm epilogue.  BM=16, BN=TN=256, grid 256.
// ---------------------------------------------------------------------------
template<int K, int FLAGS>
__global__ __launch_bounds__(256) void gemm_row(
    const ushort* __restrict__ A, const ushort* __restrict__ Bt,
    const float* __restrict__ bias, const float* __restrict__ extra,
    const float* __restrict__ resid, const float* __restrict__ pos,
    const float* __restrict__ lnS, const float* __restrict__ lnB,
    float* __restrict__ Xout, ushort* __restrict__ Hout)
{
    __shared__ ushort As[16 * 64];
    __shared__ ushort Bs[256 * 64];
    __shared__ float red[2][4][16];
    int mt = blockIdx.x;
    int row0 = mt * 16;
    int t = threadIdx.x, w = t >> 6, lane = t & 63;
    int srow = lane >> 3, slot = lane & 7;
    int gcol = (slot ^ srow) * 8;
    int sl = lane >> 4, lc = lane & 15;
    int rA = lane & 15;

    f32x4 acc[4] = {};

    #pragma unroll
    for (int k0 = 0; k0 < K; k0 += 64) {
        if (w < 2)
            gload16(A + (size_t)(row0 + w * 8 + srow) * K + k0 + gcol, As + w * 512);
        #pragma unroll
        for (int c = 0; c < 8; ++c) {
            int chunk = w * 8 + c;
            gload16(Bt + (size_t)(chunk * 8 + srow) * K + k0 + gcol, Bs + chunk * 512);
        }
        __syncthreads();
        #pragma unroll
        for (int kk = 0; kk < 2; ++kk) {
            bf16x8 a = *reinterpret_cast<const bf16x8*>(
                As + rA * 64 + (((sl + kk * 4) ^ (rA & 7)) * 8));
            #pragma unroll
            for (int n = 0; n < 4; ++n) {
                int rr = w * 64 + (lane & 15) + n * 16;
                bf16x8 b = *reinterpret_cast<const bf16x8*>(
                    Bs + rr * 64 + (((sl + kk * 4) ^ (rr & 7)) * 8));
                acc[n] = __builtin_amdgcn_mfma_f32_16x16x32_bf16(a, b, acc[n], 0, 0, 0);
            }
        }
        __syncthreads();
    }

    float v[4][4];
    float psum[4] = {}, psq[4] = {};
    #pragma unroll
    for (int n = 0; n < 4; ++n) {
        int col = w * 64 + n * 16 + lc;
        float bn = bias[col];
        float en = extra ? extra[col] : 0.f;
        #pragma unroll
        for (int r = 0; r < 4; ++r) {
            int row = row0 + sl * 4 + r;
            float x = acc[n][r] + bn;
            if constexpr (FLAGS & FG_POS) x += pos[(size_t)(row & 511) * D_ + col];
            x += en;
            if (resid) x += resid[(size_t)row * D_ + col];
            v[n][r] = x;
            psum[r] += x;
            psq[r] += x * x;
        }
    }
    #pragma unroll
    for (int r = 0; r < 4; ++r) {
        #pragma unroll
        for (int o = 8; o > 0; o >>= 1) {
            psum[r] += __shfl_xor(psum[r], o);
            psq[r]  += __shfl_xor(psq[r], o);
        }
    }
    if (lc == 0) {
        #pragma unroll
        for (int r = 0; r < 4; ++r) {
            red[0][w][sl * 4 + r] = psum[r];
            red[1][w][sl * 4 + r] = psq[r];
        }
    }
    __syncthreads();
    #pragma unroll
    for (int r = 0; r < 4; ++r) {
        int rl = sl * 4 + r;
        float s  = red[0][0][rl] + red[0][1][rl] + red[0][2][rl] + red[0][3][rl];
        float s2 = red[1][0][rl] + red[1][1][rl] + red[1][2][rl] + red[1][3][rl];
        float mean = s * (1.f / D_);
        float var = s2 * (1.f / D_) - mean * mean;
        float rstd = rsqrtf(var + 1e-5f);
        int row = row0 + rl;
        #pragma unroll
        for (int n = 0; n < 4; ++n) {
            int col = w * 64 + n * 16 + lc;
            float x = v[n][r];
            Xout[(size_t)row * D_ + col] = x;
            Hout[(size_t)row * D_ + col] =
                f2b((x - mean) * rstd * lnS[col] + lnB[col]);
        }
    }
}

// ---------------------------------------------------------------------------
// Fused FF: x_out = x + relu(h @ W1 + b1) @ W2 + b2, 16 rows per block.
// !LAST: also h_out = LN(x_out)*lnS+lnB (next layer's ln1).  LAST: xb out.
// Loops 8 chunks of 64 ff-cols; ffh passes through swizzled LDS as bf16.
// ---------------------------------------------------------------------------
template<bool LAST>
__global__ __launch_bounds__(256) void ff_fused_kernel(
    const ushort* __restrict__ H, const ushort* __restrict__ W1t,
    const ushort* __restrict__ W2t, const float* __restrict__ b1,
    const float* __restrict__ b2, const float* __restrict__ xin,
    const float* __restrict__ lnS, const float* __restrict__ lnB,
    float* __restrict__ Xout, ushort* __restrict__ Hout,
    ushort* __restrict__ XBout)
{
    __shared__ ushort As[16 * 256];     // [ks][16][64], row*64 within section
    __shared__ ushort Bs1[64 * 256];    // [ks][64][64]
    __shared__ ushort Bs2[256 * 64];    // [256][64]
    __shared__ ushort As2[16 * 64];     // ffh bf16, swizzled
    __shared__ float red[2][4][16];
    int row0 = blockIdx.x * 16;
    int t = threadIdx.x, w = t >> 6, lane = t & 63;
    int srow = lane >> 3, slot = lane & 7;
    int gcol = (slot ^ srow) * 8;
    int sl = lane >> 4, lc = lane & 15;
    int rA = lane & 15;

    // stage A = h rows row0..+15, K=256 (8 chunks; ks=chunk>>1, rbit=chunk&1)
    #pragma unroll
    for (int c = 0; c < 2; ++c) {
        int chunk = w * 2 + c;
        int ks = chunk >> 1, rbit = chunk & 1;
        gload16(H + (size_t)(row0 + rbit * 8 + srow) * 256 + ks * 64 + gcol,
                As + chunk * 512);
    }

    f32x4 xacc[4] = {};

    for (int c8 = 0; c8 < 8; ++c8) {
        int f0 = c8 * 64;
        // stage W1 chunk: rows f0..f0+63, K=256 (32 chunks; ks=c>>3, rg=c&7)
        #pragma unroll
        for (int c = 0; c < 8; ++c) {
            int chunk = w * 8 + c;
            int ks = chunk >> 3, rg = chunk & 7;
            gload16(W1t + (size_t)(f0 + rg * 8 + srow) * 256 + ks * 64 + gcol,
                    Bs1 + chunk * 512);
        }
        // stage W2 chunk: rows 0..255, cols f0..f0+63 (32 chunks)
        #pragma unroll
        for (int c = 0; c < 8; ++c) {
            int chunk = w * 8 + c;
            gload16(W2t + (size_t)(chunk * 8 + srow) * 512 + f0 + gcol,
                    Bs2 + chunk * 512);
        }
        __syncthreads();

        // GEMM1: ffh[16][64], wave w owns ff-cols w*16..+15
        f32x4 a2 = {};
        #pragma unroll
        for (int ks = 0; ks < 4; ++ks) {
            #pragma unroll
            for (int kk = 0; kk < 2; ++kk) {
                bf16x8 a = *reinterpret_cast<const bf16x8*>(
                    As + ks * 1024 + rA * 64 + (((sl + kk * 4) ^ (rA & 7)) * 8));
                int rB = w * 16 + rA;
                bf16x8 b = *reinterpret_cast<const bf16x8*>(
                    Bs1 + ks * 4096 + rB * 64 + (((sl + kk * 4) ^ (rB & 7)) * 8));
                a2 = __builtin_amdgcn_mfma_f32_16x16x32_bf16(a, b, a2, 0, 0, 0);
            }
        }
        // bias + relu -> bf16 -> As2 (swizzled, attn-Ps pattern)
        {
            float bn = b1[f0 + w * 16 + lc];
            #pragma unroll
            for (int r = 0; r < 4; ++r) {
                float p = fmaxf(a2[r] + bn, 0.f);
                int prow = sl * 4 + r;
                int pcol = w * 16 + lc;
                As2[prow * 64 + (((pcol >> 3) ^ (prow & 7)) * 8) + (pcol & 7)] = f2b(p);
            }
        }
        __syncthreads();
        // GEMM2: xacc[16][256] += ffh @ W2chunk ; wave w owns cols w*64..
        #pragma unroll
        for (int kk = 0; kk < 2; ++kk) {
            bf16x8 a = *reinterpret_cast<const bf16x8*>(
                As2 + rA * 64 + (((sl + kk * 4) ^ (rA & 7)) * 8));
            #pragma unroll
            for (int n = 0; n < 4; ++n) {
                int rB = w * 64 + n * 16 + rA;
                bf16x8 b = *reinterpret_cast<const bf16x8*>(
                    Bs2 + rB * 64 + (((sl + kk * 4) ^ (rB & 7)) * 8));
                xacc[n] = __builtin_amdgcn_mfma_f32_16x16x32_bf16(a, b, xacc[n], 0, 0, 0);
            }
        }
        __syncthreads();
    }

    // epilogue: v = xacc + b2 + x(resid)
    float v[4][4];
    float psum[4] = {}, psq[4] = {};
    #pragma unroll
    for (int n = 0; n < 4; ++n) {
        int col = w * 64 + n * 16 + lc;
        float bn = b2[col];
        #pragma unroll
        for (int r = 0; r < 4; ++r) {
            int row = row0 + sl * 4 + r;
            float x = xacc[n][r] + bn + xin[(size_t)row * D_ + col];
            v[n][r] = x;
            psum[r] += x;
            psq[r] += x * x;
        }
    }
    if constexpr (LAST) {
        #pragma unroll
        for (int n = 0; n < 4; ++n) {
            int col = w * 64 + n * 16 + lc;
            #pragma unroll
            for (int r = 0; r < 4; ++r) {
                int row = row0 + sl * 4 + r;
                XBout[(size_t)row * D_ + col] = f2b(v[n][r]);
            }
        }
        return;
    }
    #pragma unroll
    for (int r = 0; r < 4; ++r) {
        #pragma unroll
        for (int o = 8; o > 0; o >>= 1) {
            psum[r] += __shfl_xor(psum[r], o);
            psq[r]  += __shfl_xor(psq[r], o);
        }
    }
    if (lc == 0) {
        #pragma unroll
        for (int r = 0; r < 4; ++r) {
            red[0][w][sl * 4 + r] = psum[r];
            red[1][w][sl * 4 + r] = psq[r];
        }
    }
    __syncthreads();
    #pragma unroll
    for (int r = 0; r < 4; ++r) {
        int rl = sl * 4 + r;
        float s  = red[0][0][rl] + red[0][1][rl] + red[0][2][rl] + red[0][3][rl];
        float s2 = red[1][0][rl] + red[1][1][rl] + red[1][2][rl] + red[1][3][rl];
        float mean = s * (1.f / D_);
        float var = s2 * (1.f / D_) - mean * mean;
        float rstd = rsqrtf(var + 1e-5f);
        int row = row0 + rl;
        #pragma unroll
        for (int n = 0; n < 4; ++n) {
            int col = w * 64 + n * 16 + lc;
            float x = v[n][r];
            Xout[(size_t)row * D_ + col] = x;
            Hout[(size_t)row * D_ + col] =
                f2b((x - mean) * rstd * lnS[col] + lnB[col]);
        }
    }
}

// ---------------------------------------------------------------------------
// Templated bf16 MFMA GEMM (QKV + logits).
// ---------------------------------------------------------------------------
template<int BM, int BN, int K, int TN, int FLAGS>
__global__ __launch_bounds__(256) void gemm_t(
    const ushort* __restrict__ A, const ushort* __restrict__ Bt,
    const float* __restrict__ bias, const float* __restrict__ extra,
    const float* __restrict__ resid, const float* __restrict__ pos,
    float* __restrict__ Cf, ushort* __restrict__ Cb)
{
    constexpr int WM = BM / 32;
    constexpr int WN = BN / 32;
    constexpr int MT = 4096 / BM;
    constexpr int NWG = MT * (TN / BN);
    __shared__ ushort smem[(BM + BN) * 64];
    ushort* As = smem;
    ushort* Bs = smem + BM * 64;
    int bid = blockIdx.x;
    int swz = bid;
    if constexpr ((NWG & 7) == 0) {
        constexpr int cpx = NWG >> 3;
        swz = (bid & 7) * cpx + (bid >> 3);
    }
    int mt = swz % MT, nt = swz / MT;
    int row0 = mt * BM, col0 = nt * BN;
    int t = threadIdx.x, w = t >> 6, lane = t & 63;
    int wr = w >> 1, wc = w & 1;
    int srow = lane >> 3, slot = lane & 7;
    int gcol = (slot ^ srow) * 8;

    f32x4 acc[WM][WN] = {};
    int sl = lane >> 4;
    int rA0 = wr * (BM / 2) + (lane & 15);
    int rB0 = wc * (BN / 2) + (lane & 15);

    #pragma unroll
    for (int k0 = 0; k0 < K; k0 += 64) {
        #pragma unroll
        for (int c = 0; c < BM / 32; ++c) {
            int chunk = w * (BM / 32) + c;
            gload16(A + (size_t)(row0 + chunk * 8 + srow) * K + k0 + gcol,
                    As + chunk * 512);
        }
        #pragma unroll
        for (int c = 0; c < BN / 32; ++c) {
            int chunk = w * (BN / 32) + c;
            gload16(Bt + (size_t)(col0 + chunk * 8 + srow) * K + k0 + gcol,
                    Bs + chunk * 512);
        }
        __syncthreads();
        #pragma unroll
        for (int kk = 0; kk < 2; ++kk) {
            bf16x8 a[WM], b[WN];
            #pragma unroll
            for (int m = 0; m < WM; ++m) {
                int rr = rA0 + m * 16;
                a[m] = *reinterpret_cast<const bf16x8*>(
                    As + rr * 64 + (((sl + kk * 4) ^ (rr & 7)) * 8));
            }
            #pragma unroll
            for (int n = 0; n < WN; ++n) {
                int rr = rB0 + n * 16;
                b[n] = *reinterpret_cast<const bf16x8*>(
                    Bs + rr * 64 + (((sl + kk * 4) ^ (rr & 7)) * 8));
            }
            #pragma unroll
            for (int m = 0; m < WM; ++m)
                #pragma unroll
                for (int n = 0; n < WN; ++n)
                    acc[m][n] = __builtin_amdgcn_mfma_f32_16x16x32_bf16(
                        a[m], b[n], acc[m][n], 0, 0, 0);
        }
        __syncthreads();
    }

    int lr = (lane >> 4) * 4;
    int lc = lane & 15;

    if constexpr (FLAGS & FG_NT) {
        float* Ct = reinterpret_cast<float*>(smem);
        #pragma unroll
        for (int p = 0; p < 2; ++p) {
            __syncthreads();
            if (wr == p) {
                #pragma unroll
                for (int n = 0; n < WN; ++n) {
                    int colL = wc * (BN / 2) + n * 16 + lc;
                    float bn = bias[col0 + colL];
                    #pragma unroll
                    for (int m = 0; m < WM; ++m)
                        #pragma unroll
                        for (int r = 0; r < 4; ++r)
                            Ct[(m * 16 + lr + r) * BN + colL] = acc[m][n][r] + bn;
                }
            }
            __syncthreads();
            constexpr int NV4 = (BM / 2) * (BN / 4);
            #pragma unroll
            for (int j = 0; j < NV4 / 256; ++j) {
                int idx = t + j * 256;
                int rl = idx / (BN / 4);
                int c4 = idx % (BN / 4);
                f32x4 v4 = reinterpret_cast<const f32x4*>(Ct)[idx];
                __builtin_nontemporal_store(v4,
                    reinterpret_cast<f32x4*>(
                        &Cf[(size_t)(row0 + p * (BM / 2) + rl) * TN + col0 + c4 * 4]));
            }
        }
        return;
    }

    #pragma unroll
    for (int n = 0; n < WN; ++n) {
        int col = col0 + wc * (BN / 2) + n * 16 + lc;
        float bn = bias ? bias[col] : 0.f;
        float en = extra ? extra[col] : 0.f;
        #pragma unroll
        for (int m = 0; m < WM; ++m) {
            int rbase = row0 + wr * (BM / 2) + m * 16 + lr;
            #pragma unroll
            for (int r = 0; r < 4; ++r) {
                int row = rbase + r;
                float v = acc[m][n][r] + bn;
                if constexpr (FLAGS & FG_QKV) {
                    int which = col >> 8;
                    int c2 = col & 255;
                    int hh = c2 >> 6, dd = c2 & 63;
                    int bb = row >> 9, ss = row & 511;
                    if (which == 0) {
                        Cb[((((size_t)bb * NH_ + hh) * S_ + ss) << 6) + dd] =
                            f2b(v * 0.125f);
                    } else if (which == 1) {
                        (Cb + 1048576)[((((size_t)bb * NH_ + hh) * S_ + ss) << 6) + dd] =
                            f2b(v);
                    } else {
                        (Cb + 2097152)[((((size_t)bb * NH_ + hh) * HD_ + dd) << 9) + ss] =
                            f2b(v);
                    }
                } else {
                    if constexpr (FLAGS & FG_POS) v += pos[(size_t)(row & 511) * TN + col];
                    if (extra) v += en;
                    if (resid) v += resid[(size_t)row * TN + col];
                    if constexpr (FLAGS & FG_RELU) v = fmaxf(v, 0.f);
                    if constexpr (FLAGS & FG_BF16)
                        Cb[(size_t)row * TN + col] = f2b(v);
                    if constexpr (FLAGS & FG_F32)
                        Cf[(size_t)row * TN + col] = v;
                }
            }
        }
    }
}

// ---------------------------------------------------------------------------
// Fused flash attention, K/V double-buffered.
// ---------------------------------------------------------------------------
__global__ __launch_bounds__(256) void attn_kernel(
    const ushort* __restrict__ q, const ushort* __restrict__ k,
    const ushort* __restrict__ vT, ushort* __restrict__ pv)
{
    int qt = blockIdx.x, bh = blockIdx.y;
    __shared__ ushort smem[20480];
    ushort* Ps = smem + 16384;
    int t = threadIdx.x, w = t >> 6, lane = t & 63;
    int srow = lane >> 3, slot = lane & 7;
    int gcol = (slot ^ srow) * 8;
    int sl = lane >> 4, lc = lane & 15;

    const ushort* Qp = q + ((size_t)bh * S_ + qt * 64) * HD_;
    const ushort* Kp = k + (size_t)bh * S_ * HD_;
    const ushort* Vp = vT + (size_t)bh * HD_ * S_;

    int qrow = w * 16 + lc;
    bf16x8 qf0 = *reinterpret_cast<const bf16x8*>(Qp + qrow * 64 + sl * 8);
    bf16x8 qf1 = *reinterpret_cast<const bf16x8*>(Qp + qrow * 64 + sl * 8 + 32);

    f32x4 o[4] = {};
    float m_r[4], l_r[4];
    #pragma unroll
    for (int r = 0; r < 4; ++r) { m_r[r] = -1e30f; l_r[r] = 0.f; }
    int row_abs = qt * 64 + w * 16 + sl * 4;

    {
        ushort* Ks = smem;
        ushort* Vs = smem + 4096;
        #pragma unroll
        for (int c = 0; c < 2; ++c) {
            int chunk = w * 2 + c;
            gload16(Kp + (size_t)(chunk * 8 + srow) * 64 + gcol, Ks + chunk * 512);
            gload16(Vp + (size_t)(chunk * 8 + srow) * 512 + gcol, Vs + chunk * 512);
        }
    }

    for (int kt = 0; kt <= qt; ++kt) {
        int cur = kt & 1;
        ushort* Ks = smem + cur * 8192;
        ushort* Vs = smem + cur * 8192 + 4096;
        __syncthreads();
        if (kt < qt) {
            ushort* Kn = smem + (cur ^ 1) * 8192;
            ushort* Vn = Kn + 4096;
            #pragma unroll
            for (int c = 0; c < 2; ++c) {
                int chunk = w * 2 + c;
                gload16(Kp + (size_t)((kt + 1) * 64 + chunk * 8 + srow) * 64 + gcol,
                        Kn + chunk * 512);
                gload16(Vp + (size_t)(chunk * 8 + srow) * 512 + (kt + 1) * 64 + gcol,
                        Vn + chunk * 512);
            }
        }

        f32x4 sa[4] = {};
        #pragma unroll
        for (int n = 0; n < 4; ++n) {
            int rB = n * 16 + lc;
            bf16x8 b0 = *reinterpret_cast<const bf16x8*>(
                Ks + rB * 64 + ((sl ^ (rB & 7)) * 8));
            bf16x8 b1 = *reinterpret_cast<const bf16x8*>(
                Ks + rB * 64 + (((sl + 4) ^ (rB & 7)) * 8));
            sa[n] = __builtin_amdgcn_mfma_f32_16x16x32_bf16(qf0, b0, sa[n], 0, 0, 0);
            sa[n] = __builtin_amdgcn_mfma_f32_16x16x32_bf16(qf1, b1, sa[n], 0, 0, 0);
        }
        if (kt == qt) {
            #pragma unroll
            for (int n = 0; n < 4; ++n) {
                int col = kt * 64 + n * 16 + lc;
                #pragma unroll
                for (int r = 0; r < 4; ++r)
                    if (col > row_abs + r) sa[n][r] = -1e30f;
            }
        }
        float psum[4];
        #pragma unroll
        for (int r = 0; r < 4; ++r) {
            float vm = fmaxf(fmaxf(sa[0][r], sa[1][r]), fmaxf(sa[2][r], sa[3][r]));
            vm = fmaxf(vm, __shfl_xor(vm, 1));
            vm = fmaxf(vm, __shfl_xor(vm, 2));
            vm = fmaxf(vm, __shfl_xor(vm, 4));
            vm = fmaxf(vm, __shfl_xor(vm, 8));
            float mn = fmaxf(m_r[r], vm);
            float scl = __expf(m_r[r] - mn);
            m_r[r] = mn;
            l_r[r] *= scl;
            #pragma unroll
            for (int n = 0; n < 4; ++n) o[n][r] *= scl;
            psum[r] = 0.f;
        }
        ushort* Pw = Ps + w * 1024;
        #pragma unroll
        for (int n = 0; n < 4; ++n) {
            #pragma unroll
            for (int r = 0; r < 4; ++r) {
                float p = __expf(sa[n][r] - m_r[r]);
                psum[r] += p;
                int prow = sl * 4 + r;
                int pcol = n * 16 + lc;
                int pslot = pcol >> 3;
                Pw[prow * 64 + ((pslot ^ (prow & 7)) * 8) + (pcol & 7)] = f2b(p);
            }
        }
        #pragma unroll
        for (int r = 0; r < 4; ++r) {
            float s = psum[r];
            s += __shfl_xor(s, 1);
            s += __shfl_xor(s, 2);
            s += __shfl_xor(s, 4);
            s += __shfl_xor(s, 8);
            l_r[r] += s;
        }
        int arow = lc;
        bf16x8 pa0 = *reinterpret_cast<const bf16x8*>(
            Pw + arow * 64 + ((sl ^ (arow & 7)) * 8));
        bf16x8 pa1 = *reinterpret_cast<const bf16x8*>(
            Pw + arow * 64 + (((sl + 4) ^ (arow & 7)) * 8));
        #pragma unroll
        for (int n = 0; n < 4; ++n) {
            int rB = n * 16 + lc;
            bf16x8 v0 = *reinterpret_cast<const bf16x8*>(
                Vs + rB * 64 + ((sl ^ (rB & 7)) * 8));
            bf16x8 v1 = *reinterpret_cast<const bf16x8*>(
                Vs + rB * 64 + (((sl + 4) ^ (rB & 7)) * 8));
            o[n] = __builtin_amdgcn_mfma_f32_16x16x32_bf16(pa0, v0, o[n], 0, 0, 0);
            o[n] = __builtin_amdgcn_mfma_f32_16x16x32_bf16(pa1, v1, o[n], 0, 0, 0);
        }
    }

    int bb = bh >> 2, hh = bh & 3;
    #pragma unroll
    for (int r = 0; r < 4; ++r) {
        float inv = 1.f / l_r[r];
        int ss = qt * 64 + w * 16 + sl * 4 + r;
        #pragma unroll
        for (int n = 0; n < 4; ++n) {
            int dd = n * 16 + lc;
            pv[((size_t)bb * S_ + ss) * D_ + hh * HD_ + dd] = f2b(o[n][r] * inv);
        }
    }
}

// ===========================================================================
extern "C" void kernel_launch(void* const* d_in, const int* in_sizes, int n_in,
                              void* d_out, int out_size, void* d_ws, size_t ws_size,
                              hipStream_t stream)
{
    const int*   tok     = (const int*)  d_in[0];
    const float* ram     = (const float*)d_in[1];
    const float* proj_W  = (const float*)d_in[2];
    const float* proj_b  = (const float*)d_in[3];
    const float* pos_emb = (const float*)d_in[4];
    const float* sa_Wq   = (const float*)d_in[5];
    const float* sa_Wk   = (const float*)d_in[6];
    const float* sa_Wv   = (const float*)d_in[7];
    const float* sa_Wo   = (const float*)d_in[8];
    const float* sa_bq   = (const float*)d_in[9];
    const float* sa_bk   = (const float*)d_in[10];
    const float* sa_bv   = (const float*)d_in[11];
    const float* sa_bo   = (const float*)d_in[12];
    const float* ca_Wo   = (const float*)d_in[16];
    const float* ca_bv   = (const float*)d_in[19];
    const float* ca_bo   = (const float*)d_in[20];
    const float* ln1_s   = (const float*)d_in[21];
    const float* ln1_b   = (const float*)d_in[22];
    const float* ln3_s   = (const float*)d_in[25];
    const float* ln3_b   = (const float*)d_in[26];
    const float* ff_W1   = (const float*)d_in[27];
    const float* ff_b1   = (const float*)d_in[28];
    const float* ff_W2   = (const float*)d_in[29];
    const float* ff_b2   = (const float*)d_in[30];
    const float* out_W   = (const float*)d_in[31];
    const float* out_b   = (const float*)d_in[32];

    float* out = (float*)d_out;
    float* ws  = (float*)d_ws;

    // ws (must survive to logits): x | cc | xb | Wb
    float*  x   = ws;                            // BS_*D_ f32
    float*  cc  = ws + (size_t)BS_ * D_;         // L_*D_ f32
    ushort* xb  = (ushort*)(cc + L_ * D_);       // BS_*D_ bf16
    ushort* Wb  = xb + (size_t)BS_ * D_;         // V_*D_ bf16

    // d_out scratch (fully overwritten by the logits GEMM)
    ushort* sc_b  = (ushort*)out;                // 2,097,152
    ushort* h_b   = sc_b + 2097152;              // 1,048,576
    ushort* qkv3  = h_b + 1048576;               // 3,145,728 (q|k|vT)
    ushort* pv_b  = qkv3 + 3145728;              // 1,048,576
    ushort* pjWb  = pv_b + 1048576;              // 131,072
    ushort* WqkvB = pjWb + 131072;               // 786,432  [L][768][256]
    ushort* WoB   = WqkvB + 786432;              // 262,144
    ushort* ff1B  = WoB + 262144;                // 524,288
    ushort* ff2B  = ff1B + 524288;               // 524,288
    float*  qkvb  = (float*)(ff2B + 524288);     // 4096 f32 (L*768 used)
    ushort* qb_b  = qkv3;
    ushort* kb_b  = qkv3 + 1048576;
    ushort* vT_b  = qkv3 + 2097152;

    prologue_kernel<<<14276, 256, 0, stream>>>(
        tok, ram, proj_W, sa_Wq, sa_Wk, sa_Wv, sa_Wo, ff_W1, ff_W2, out_W,
        ca_bv, ca_Wo, ca_bo, sa_bq, sa_bk, sa_bv,
        pjWb, WqkvB, WoB, ff1B, ff2B, Wb, cc, qkvb, sc_b);

    // x = scores @ proj_W + proj_b + pos_emb; h_b = ln1_0(x)   (fused)
    gemm_row<512, FG_POS><<<256, 256, 0, stream>>>(
        sc_b, pjWb, proj_b, nullptr, nullptr, pos_emb,
        ln1_s, ln1_b, x, h_b);

    for (int l = 0; l < L_; ++l) {
        gemm_t<64, 64, 256, 768, FG_QKV><<<768, 256, 0, stream>>>(
            h_b, WqkvB + (size_t)l * 196608, qkvb + l * 768,
            nullptr, nullptr, nullptr, nullptr, qkv3);
        attn_kernel<<<dim3(8, 32), 256, 0, stream>>>(qb_b, kb_b, vT_b, pv_b);
        // x = x + pv @ Wo + bo + cc[l]; h_b = ln3(x)   (fused)
        gemm_row<256, 0><<<256, 256, 0, stream>>>(
            pv_b, WoB + (size_t)l * 65536, sa_bo + l * D_,
            cc + l * D_, x, nullptr, ln3_s + l * D_, ln3_b + l * D_, x, h_b);
        // fused FF: x = x + relu(h@W1+b1)@W2 + b2 ; h = ln1_{l+1}(x) or xb out
        if (l < L_ - 1) {
            ff_fused_kernel<false><<<256, 256, 0, stream>>>(
                h_b, ff1B + (size_t)l * 131072, ff2B + (size_t)l * 131072,
                ff_b1 + l * FF_, ff_b2 + l * D_, x,
                ln1_s + (l + 1) * D_, ln1_b + (l + 1) * D_, x, h_b, nullptr);
        } else {
            ff_fused_kernel<true><<<256, 256, 0, stream>>>(
                h_b, ff1B + (size_t)l * 131072, ff2B + (size_t)l * 131072,
                ff_b1 + l * FF_, ff_b2 + l * D_, x,
                nullptr, nullptr, nullptr, nullptr, xb);
        }
    }

    // logits = xb @ Wb^T + out_b  (overwrites all of d_out)
    gemm_t<128, 128, 256, 32000, FG_F32 | FG_NT><<<8000, 256, 0, stream>>>(
        xb, Wb, out_b, nullptr, nullptr, nullptr, out, nullptr);
}

// Round 12
// 350.223 us; speedup vs baseline: 8.8121x; 1.0853x over previous
//
#include <hip/hip_runtime.h>

#define B_   8
#define S_   512
#define V_   32000
#define CTX_ 8
#define NC_  512
#define D_   256
#define NH_  4
#define L_   4
#define FF_  512
#define HD_  64
#define BS_  4096   // B_*S_

#define FG_F32   1
#define FG_BF16  2
#define FG_RELU  4
#define FG_POS   8
#define FG_NT    16
#define FG_QKV   32

typedef __attribute__((ext_vector_type(8))) short bf16x8;
typedef __attribute__((ext_vector_type(4))) float f32x4;

__device__ inline void gload16(const void* g, void* lds) {
    __builtin_amdgcn_global_load_lds(
        (const __attribute__((address_space(1))) void*)g,
        (__attribute__((address_space(3))) void*)lds, 16, 0, 0);
}

__device__ inline ushort f2b(float f) {   // f32 -> bf16 RNE
    union { float f; unsigned u; } v; v.f = f;
    unsigned u = v.u;
    unsigned r = u + 0x7fffu + ((u >> 16) & 1u);
    return (ushort)(r >> 16);
}

// ---------------------------------------------------------------------------
// Prologue (ONE launch): flat job grid.
// ---------------------------------------------------------------------------
__global__ __launch_bounds__(256) void prologue_kernel(
    const int* __restrict__ tok, const float* __restrict__ ram,
    const float* __restrict__ proj_W, const float* __restrict__ Wq,
    const float* __restrict__ Wk, const float* __restrict__ Wv,
    const float* __restrict__ Wo, const float* __restrict__ W1,
    const float* __restrict__ W2, const float* __restrict__ outW,
    const float* __restrict__ ca_bv, const float* __restrict__ ca_Wo,
    const float* __restrict__ ca_bo, const float* __restrict__ bq,
    const float* __restrict__ bk, const float* __restrict__ bv,
    ushort* __restrict__ pjWb, ushort* __restrict__ WqkvB,
    ushort* __restrict__ WoB, ushort* __restrict__ ff1B,
    ushort* __restrict__ ff2B, ushort* __restrict__ Wb,
    float* __restrict__ cc, float* __restrict__ qkvb,
    ushort* __restrict__ scores)
{
    __shared__ float tile[32 * 33];
    int id = blockIdx.x;
    int t = threadIdx.x;
    if (id < 10176) {
        const float* src; ushort* dst; int K, N, lt;
        if (id < 128)       { src = proj_W; dst = pjWb; K = 512; N = 256; lt = id; }
        else if (id < 896)  { lt = id - 128; int z = lt >> 6; lt &= 63;
                              int which = z / L_, l = z % L_;
                              src = (which == 0 ? Wq : which == 1 ? Wk : Wv) + (size_t)l * 65536;
                              dst = WqkvB + ((size_t)l * 768 + which * 256) * 256;
                              K = 256; N = 256; }
        else if (id < 1152) { lt = id - 896; int l = lt >> 6; lt &= 63;
                              src = Wo + (size_t)l * 65536; dst = WoB + (size_t)l * 65536;
                              K = 256; N = 256; }
        else if (id < 1664) { lt = id - 1152; int l = lt >> 7; lt &= 127;
                              src = W1 + (size_t)l * 131072; dst = ff1B + (size_t)l * 131072;
                              K = 256; N = 512; }
        else if (id < 2176) { lt = id - 1664; int l = lt >> 7; lt &= 127;
                              src = W2 + (size_t)l * 131072; dst = ff2B + (size_t)l * 131072;
                              K = 512; N = 256; }
        else                { lt = id - 2176; src = outW; dst = Wb; K = 256; N = 32000; }
        int ntc = N >> 5;
        int n0 = (lt % ntc) * 32, k0 = (lt / ntc) * 32;
        int tx = t & 31, ty = t >> 5;
        for (int i = ty; i < 32; i += 8)
            tile[i * 33 + tx] = src[(size_t)(k0 + i) * N + n0 + tx];
        __syncthreads();
        for (int i = ty; i < 32; i += 8)
            dst[(size_t)(n0 + i) * K + k0 + tx] = f2b(tile[tx * 33 + i]);
    } else if (id < 10180) {
        int l = id - 10176;
        const float* w = ca_Wo + (size_t)l * D_ * D_;
        const float* b = ca_bv + l * D_;
        float acc = 0.f;
        for (int d = 0; d < D_; ++d) acc += b[d] * w[(size_t)d * D_ + t];
        cc[l * D_ + t] = acc + ca_bo[l * D_ + t];
        for (int u = t; u < 768; u += 256) {
            int which = u >> 8, c = u & 255;
            const float* src = which == 0 ? bq : which == 1 ? bk : bv;
            qkvb[l * 768 + u] = src[l * 256 + c];
        }
    } else {
        int bs = id - 10180;
        int b = bs >> 9, s = bs & 511;
        float a0 = 0.f, a1 = 0.f;
        #pragma unroll
        for (int c = 0; c < CTX_; ++c) {
            int pos = s + c - (CTX_ - 1);
            int tk = (pos < 0) ? 0 : tok[b * S_ + pos];
            const float* row = ram + (size_t)tk * NC_;
            a0 += row[t];
            a1 += row[t + 256];
        }
        scores[(size_t)bs * NC_ + t]       = f2b(a0 * 0.125f);
        scores[(size_t)bs * NC_ + t + 256] = f2b(a1 * 0.125f);
    }
}

// ---------------------------------------------------------------------------
// Row-GEMM with fused LayerNorm epilogue (proj only).  BM=16, BN=256.
// ---------------------------------------------------------------------------
template<int K, int FLAGS>
__global__ __launch_bounds__(256) void gemm_row(
    const ushort* __restrict__ A, const ushort* __restrict__ Bt,
    const float* __restrict__ bias, const float* __restrict__ extra,
    const float* __restrict__ resid, const float* __restrict__ pos,
    const float* __restrict__ lnS, const float* __restrict__ lnB,
    float* __restrict__ Xout, ushort* __restrict__ Hout)
{
    __shared__ ushort As[16 * 64];
    __shared__ ushort Bs[256 * 64];
    __shared__ float red[2][4][16];
    int mt = blockIdx.x;
    int row0 = mt * 16;
    int t = threadIdx.x, w = t >> 6, lane = t & 63;
    int srow = lane >> 3, slot = lane & 7;
    int gcol = (slot ^ srow) * 8;
    int sl = lane >> 4, lc = lane & 15;
    int rA = lane & 15;

    f32x4 acc[4] = {};

    #pragma unroll
    for (int k0 = 0; k0 < K; k0 += 64) {
        if (w < 2)
            gload16(A + (size_t)(row0 + w * 8 + srow) * K + k0 + gcol, As + w * 512);
        #pragma unroll
        for (int c = 0; c < 8; ++c) {
            int chunk = w * 8 + c;
            gload16(Bt + (size_t)(chunk * 8 + srow) * K + k0 + gcol, Bs + chunk * 512);
        }
        __syncthreads();
        #pragma unroll
        for (int kk = 0; kk < 2; ++kk) {
            bf16x8 a = *reinterpret_cast<const bf16x8*>(
                As + rA * 64 + (((sl + kk * 4) ^ (rA & 7)) * 8));
            #pragma unroll
            for (int n = 0; n < 4; ++n) {
                int rr = w * 64 + (lane & 15) + n * 16;
                bf16x8 b = *reinterpret_cast<const bf16x8*>(
                    Bs + rr * 64 + (((sl + kk * 4) ^ (rr & 7)) * 8));
                acc[n] = __builtin_amdgcn_mfma_f32_16x16x32_bf16(a, b, acc[n], 0, 0, 0);
            }
        }
        __syncthreads();
    }

    float v[4][4];
    float psum[4] = {}, psq[4] = {};
    #pragma unroll
    for (int n = 0; n < 4; ++n) {
        int col = w * 64 + n * 16 + lc;
        float bn = bias[col];
        float en = extra ? extra[col] : 0.f;
        #pragma unroll
        for (int r = 0; r < 4; ++r) {
            int row = row0 + sl * 4 + r;
            float x = acc[n][r] + bn;
            if constexpr (FLAGS & FG_POS) x += pos[(size_t)(row & 511) * D_ + col];
            x += en;
            if (resid) x += resid[(size_t)row * D_ + col];
            v[n][r] = x;
            psum[r] += x;
            psq[r] += x * x;
        }
    }
    #pragma unroll
    for (int r = 0; r < 4; ++r) {
        #pragma unroll
        for (int o = 8; o > 0; o >>= 1) {
            psum[r] += __shfl_xor(psum[r], o);
            psq[r]  += __shfl_xor(psq[r], o);
        }
    }
    if (lc == 0) {
        #pragma unroll
        for (int r = 0; r < 4; ++r) {
            red[0][w][sl * 4 + r] = psum[r];
            red[1][w][sl * 4 + r] = psq[r];
        }
    }
    __syncthreads();
    #pragma unroll
    for (int r = 0; r < 4; ++r) {
        int rl = sl * 4 + r;
        float s  = red[0][0][rl] + red[0][1][rl] + red[0][2][rl] + red[0][3][rl];
        float s2 = red[1][0][rl] + red[1][1][rl] + red[1][2][rl] + red[1][3][rl];
        float mean = s * (1.f / D_);
        float var = s2 * (1.f / D_) - mean * mean;
        float rstd = rsqrtf(var + 1e-5f);
        int row = row0 + rl;
        #pragma unroll
        for (int n = 0; n < 4; ++n) {
            int col = w * 64 + n * 16 + lc;
            float x = v[n][r];
            Xout[(size_t)row * D_ + col] = x;
            Hout[(size_t)row * D_ + col] =
                f2b((x - mean) * rstd * lnS[col] + lnB[col]);
        }
    }
}

// ---------------------------------------------------------------------------
// Fused layer tail (16 rows/block, grid 256):
//   x1 = pv @ Wo^T + bo + cc + x          (o-proj + residual)
//   h  = LN3(x1)          -> LDS only (never global)
//   x2 = x1 + relu(h @ W1 + b1) @ W2 + b2 (FF, x1 kept in registers)
//   !LAST: Xout = x2, Hout = LN1next(x2);  LAST: XBout = bf16(x2)
// ---------------------------------------------------------------------------
template<bool LAST>
__global__ __launch_bounds__(256) void tail_fused_kernel(
    const ushort* __restrict__ pv, const ushort* __restrict__ WoT,
    const float* __restrict__ bo, const float* __restrict__ ccl,
    const float* __restrict__ xin,
    const float* __restrict__ ln3S, const float* __restrict__ ln3B,
    const ushort* __restrict__ W1t, const ushort* __restrict__ W2t,
    const float* __restrict__ b1, const float* __restrict__ b2,
    const float* __restrict__ ln1S, const float* __restrict__ ln1B,
    float* __restrict__ Xout, ushort* __restrict__ Hout,
    ushort* __restrict__ XBout)
{
    __shared__ ushort Ah[16 * 256];     // h bf16, gload16-compatible swizzle
    __shared__ ushort As1[16 * 64];
    __shared__ ushort Bs1[64 * 256];    // FF W1 chunk
    __shared__ ushort Bs2[256 * 64];    // o-proj Wo / FF W2 chunk
    __shared__ ushort As2[16 * 64];     // ffh bf16, swizzled
    __shared__ float red[2][4][16];
    int row0 = blockIdx.x * 16;
    int t = threadIdx.x, w = t >> 6, lane = t & 63;
    int srow = lane >> 3, slot = lane & 7;
    int gcol = (slot ^ srow) * 8;
    int sl = lane >> 4, lc = lane & 15;
    int rA = lane & 15;

    // ---- Phase 1: o-proj ----
    f32x4 acc[4] = {};
    #pragma unroll
    for (int k0 = 0; k0 < 256; k0 += 64) {
        if (w < 2)
            gload16(pv + (size_t)(row0 + w * 8 + srow) * 256 + k0 + gcol, As1 + w * 512);
        #pragma unroll
        for (int c = 0; c < 8; ++c) {
            int chunk = w * 8 + c;
            gload16(WoT + (size_t)(chunk * 8 + srow) * 256 + k0 + gcol, Bs2 + chunk * 512);
        }
        __syncthreads();
        #pragma unroll
        for (int kk = 0; kk < 2; ++kk) {
            bf16x8 a = *reinterpret_cast<const bf16x8*>(
                As1 + rA * 64 + (((sl + kk * 4) ^ (rA & 7)) * 8));
            #pragma unroll
            for (int n = 0; n < 4; ++n) {
                int rr = w * 64 + rA + n * 16;
                bf16x8 b = *reinterpret_cast<const bf16x8*>(
                    Bs2 + rr * 64 + (((sl + kk * 4) ^ (rr & 7)) * 8));
                acc[n] = __builtin_amdgcn_mfma_f32_16x16x32_bf16(a, b, acc[n], 0, 0, 0);
            }
        }
        __syncthreads();
    }

    // epilogue 1: x1 in registers; LN3 -> Ah (LDS only)
    float v[4][4];
    {
        float psum[4] = {}, psq[4] = {};
        #pragma unroll
        for (int n = 0; n < 4; ++n) {
            int col = w * 64 + n * 16 + lc;
            float bn = bo[col] + ccl[col];
            #pragma unroll
            for (int r = 0; r < 4; ++r) {
                int row = row0 + sl * 4 + r;
                float x = acc[n][r] + bn + xin[(size_t)row * D_ + col];
                v[n][r] = x;
                psum[r] += x;
                psq[r] += x * x;
            }
        }
        #pragma unroll
        for (int r = 0; r < 4; ++r) {
            #pragma unroll
            for (int o = 8; o > 0; o >>= 1) {
                psum[r] += __shfl_xor(psum[r], o);
                psq[r]  += __shfl_xor(psq[r], o);
            }
        }
        if (lc == 0) {
            #pragma unroll
            for (int r = 0; r < 4; ++r) {
                red[0][w][sl * 4 + r] = psum[r];
                red[1][w][sl * 4 + r] = psq[r];
            }
        }
        __syncthreads();
        #pragma unroll
        for (int r = 0; r < 4; ++r) {
            int rl = sl * 4 + r;
            float s  = red[0][0][rl] + red[0][1][rl] + red[0][2][rl] + red[0][3][rl];
            float s2 = red[1][0][rl] + red[1][1][rl] + red[1][2][rl] + red[1][3][rl];
            float mean = s * (1.f / D_);
            float var = s2 * (1.f / D_) - mean * mean;
            float rstd = rsqrtf(var + 1e-5f);
            #pragma unroll
            for (int n = 0; n < 4; ++n) {
                int col = w * 64 + n * 16 + lc;   // ks = w, colk = n*16+lc
                int colk = n * 16 + lc;
                float h = (v[n][r] - mean) * rstd * ln3S[col] + ln3B[col];
                Ah[w * 1024 + rl * 64 + (((colk >> 3) ^ (rl & 7)) * 8) + (colk & 7)] =
                    f2b(h);
            }
        }
    }
    __syncthreads();

    // ---- Phase 2: FF ----
    f32x4 xacc[4] = {};
    for (int c8 = 0; c8 < 8; ++c8) {
        int f0 = c8 * 64;
        #pragma unroll
        for (int c = 0; c < 8; ++c) {
            int chunk = w * 8 + c;
            int ks = chunk >> 3, rg = chunk & 7;
            gload16(W1t + (size_t)(f0 + rg * 8 + srow) * 256 + ks * 64 + gcol,
                    Bs1 + chunk * 512);
        }
        #pragma unroll
        for (int c = 0; c < 8; ++c) {
            int chunk = w * 8 + c;
            gload16(W2t + (size_t)(chunk * 8 + srow) * 512 + f0 + gcol,
                    Bs2 + chunk * 512);
        }
        __syncthreads();

        f32x4 a2 = {};
        #pragma unroll
        for (int ks = 0; ks < 4; ++ks) {
            #pragma unroll
            for (int kk = 0; kk < 2; ++kk) {
                bf16x8 a = *reinterpret_cast<const bf16x8*>(
                    Ah + ks * 1024 + rA * 64 + (((sl + kk * 4) ^ (rA & 7)) * 8));
                int rB = w * 16 + rA;
                bf16x8 b = *reinterpret_cast<const bf16x8*>(
                    Bs1 + ks * 4096 + rB * 64 + (((sl + kk * 4) ^ (rB & 7)) * 8));
                a2 = __builtin_amdgcn_mfma_f32_16x16x32_bf16(a, b, a2, 0, 0, 0);
            }
        }
        {
            float bn = b1[f0 + w * 16 + lc];
            #pragma unroll
            for (int r = 0; r < 4; ++r) {
                float p = fmaxf(a2[r] + bn, 0.f);
                int prow = sl * 4 + r;
                int pcol = w * 16 + lc;
                As2[prow * 64 + (((pcol >> 3) ^ (prow & 7)) * 8) + (pcol & 7)] = f2b(p);
            }
        }
        __syncthreads();
        #pragma unroll
        for (int kk = 0; kk < 2; ++kk) {
            bf16x8 a = *reinterpret_cast<const bf16x8*>(
                As2 + rA * 64 + (((sl + kk * 4) ^ (rA & 7)) * 8));
            #pragma unroll
            for (int n = 0; n < 4; ++n) {
                int rB = w * 64 + n * 16 + rA;
                bf16x8 b = *reinterpret_cast<const bf16x8*>(
                    Bs2 + rB * 64 + (((sl + kk * 4) ^ (rB & 7)) * 8));
                xacc[n] = __builtin_amdgcn_mfma_f32_16x16x32_bf16(a, b, xacc[n], 0, 0, 0);
            }
        }
        __syncthreads();
    }

    // epilogue 2: x2 = xacc + b2 + x1(v)
    float psum[4] = {}, psq[4] = {};
    #pragma unroll
    for (int n = 0; n < 4; ++n) {
        int col = w * 64 + n * 16 + lc;
        float bn = b2[col];
        #pragma unroll
        for (int r = 0; r < 4; ++r) {
            float x = xacc[n][r] + bn + v[n][r];
            v[n][r] = x;
            psum[r] += x;
            psq[r] += x * x;
        }
    }
    if constexpr (LAST) {
        #pragma unroll
        for (int n = 0; n < 4; ++n) {
            int col = w * 64 + n * 16 + lc;
            #pragma unroll
            for (int r = 0; r < 4; ++r) {
                int row = row0 + sl * 4 + r;
                XBout[(size_t)row * D_ + col] = f2b(v[n][r]);
            }
        }
        return;
    }
    #pragma unroll
    for (int r = 0; r < 4; ++r) {
        #pragma unroll
        for (int o = 8; o > 0; o >>= 1) {
            psum[r] += __shfl_xor(psum[r], o);
            psq[r]  += __shfl_xor(psq[r], o);
        }
    }
    if (lc == 0) {
        #pragma unroll
        for (int r = 0; r < 4; ++r) {
            red[0][w][sl * 4 + r] = psum[r];
            red[1][w][sl * 4 + r] = psq[r];
        }
    }
    __syncthreads();
    #pragma unroll
    for (int r = 0; r < 4; ++r) {
        int rl = sl * 4 + r;
        float s  = red[0][0][rl] + red[0][1][rl] + red[0][2][rl] + red[0][3][rl];
        float s2 = red[1][0][rl] + red[1][1][rl] + red[1][2][rl] + red[1][3][rl];
        float mean = s * (1.f / D_);
        float var = s2 * (1.f / D_) - mean * mean;
        float rstd = rsqrtf(var + 1e-5f);
        int row = row0 + rl;
        #pragma unroll
        for (int n = 0; n < 4; ++n) {
            int col = w * 64 + n * 16 + lc;
            float x = v[n][r];
            Xout[(size_t)row * D_ + col] = x;
            Hout[(size_t)row * D_ + col] =
                f2b((x - mean) * rstd * ln1S[col] + ln1B[col]);
        }
    }
}

// ---------------------------------------------------------------------------
// Templated bf16 MFMA GEMM (QKV + logits).
// ---------------------------------------------------------------------------
template<int BM, int BN, int K, int TN, int FLAGS>
__global__ __launch_bounds__(256) void gemm_t(
    const ushort* __restrict__ A, const ushort* __restrict__ Bt,
    const float* __restrict__ bias, const float* __restrict__ extra,
    const float* __restrict__ resid, const float* __restrict__ pos,
    float* __restrict__ Cf, ushort* __restrict__ Cb)
{
    constexpr int WM = BM / 32;
    constexpr int WN = BN / 32;
    constexpr int MT = 4096 / BM;
    constexpr int NWG = MT * (TN / BN);
    __shared__ ushort smem[(BM + BN) * 64];
    ushort* As = smem;
    ushort* Bs = smem + BM * 64;
    int bid = blockIdx.x;
    int swz = bid;
    if constexpr ((NWG & 7) == 0) {
        constexpr int cpx = NWG >> 3;
        swz = (bid & 7) * cpx + (bid >> 3);
    }
    int mt = swz % MT, nt = swz / MT;
    int row0 = mt * BM, col0 = nt * BN;
    int t = threadIdx.x, w = t >> 6, lane = t & 63;
    int wr = w >> 1, wc = w & 1;
    int srow = lane >> 3, slot = lane & 7;
    int gcol = (slot ^ srow) * 8;

    f32x4 acc[WM][WN] = {};
    int sl = lane >> 4;
    int rA0 = wr * (BM / 2) + (lane & 15);
    int rB0 = wc * (BN / 2) + (lane & 15);

    #pragma unroll
    for (int k0 = 0; k0 < K; k0 += 64) {
        #pragma unroll
        for (int c = 0; c < BM / 32; ++c) {
            int chunk = w * (BM / 32) + c;
            gload16(A + (size_t)(row0 + chunk * 8 + srow) * K + k0 + gcol,
                    As + chunk * 512);
        }
        #pragma unroll
        for (int c = 0; c < BN / 32; ++c) {
            int chunk = w * (BN / 32) + c;
            gload16(Bt + (size_t)(col0 + chunk * 8 + srow) * K + k0 + gcol,
                    Bs + chunk * 512);
        }
        __syncthreads();
        #pragma unroll
        for (int kk = 0; kk < 2; ++kk) {
            bf16x8 a[WM], b[WN];
            #pragma unroll
            for (int m = 0; m < WM; ++m) {
                int rr = rA0 + m * 16;
                a[m] = *reinterpret_cast<const bf16x8*>(
                    As + rr * 64 + (((sl + kk * 4) ^ (rr & 7)) * 8));
            }
            #pragma unroll
            for (int n = 0; n < WN; ++n) {
                int rr = rB0 + n * 16;
                b[n] = *reinterpret_cast<const bf16x8*>(
                    Bs + rr * 64 + (((sl + kk * 4) ^ (rr & 7)) * 8));
            }
            #pragma unroll
            for (int m = 0; m < WM; ++m)
                #pragma unroll
                for (int n = 0; n < WN; ++n)
                    acc[m][n] = __builtin_amdgcn_mfma_f32_16x16x32_bf16(
                        a[m], b[n], acc[m][n], 0, 0, 0);
        }
        __syncthreads();
    }

    int lr = (lane >> 4) * 4;
    int lc = lane & 15;

    if constexpr (FLAGS & FG_NT) {
        float* Ct = reinterpret_cast<float*>(smem);
        #pragma unroll
        for (int p = 0; p < 2; ++p) {
            __syncthreads();
            if (wr == p) {
                #pragma unroll
                for (int n = 0; n < WN; ++n) {
                    int colL = wc * (BN / 2) + n * 16 + lc;
                    float bn = bias[col0 + colL];
                    #pragma unroll
                    for (int m = 0; m < WM; ++m)
                        #pragma unroll
                        for (int r = 0; r < 4; ++r)
                            Ct[(m * 16 + lr + r) * BN + colL] = acc[m][n][r] + bn;
                }
            }
            __syncthreads();
            constexpr int NV4 = (BM / 2) * (BN / 4);
            #pragma unroll
            for (int j = 0; j < NV4 / 256; ++j) {
                int idx = t + j * 256;
                int rl = idx / (BN / 4);
                int c4 = idx % (BN / 4);
                f32x4 v4 = reinterpret_cast<const f32x4*>(Ct)[idx];
                __builtin_nontemporal_store(v4,
                    reinterpret_cast<f32x4*>(
                        &Cf[(size_t)(row0 + p * (BM / 2) + rl) * TN + col0 + c4 * 4]));
            }
        }
        return;
    }

    #pragma unroll
    for (int n = 0; n < WN; ++n) {
        int col = col0 + wc * (BN / 2) + n * 16 + lc;
        float bn = bias ? bias[col] : 0.f;
        float en = extra ? extra[col] : 0.f;
        #pragma unroll
        for (int m = 0; m < WM; ++m) {
            int rbase = row0 + wr * (BM / 2) + m * 16 + lr;
            #pragma unroll
            for (int r = 0; r < 4; ++r) {
                int row = rbase + r;
                float v = acc[m][n][r] + bn;
                if constexpr (FLAGS & FG_QKV) {
                    int which = col >> 8;
                    int c2 = col & 255;
                    int hh = c2 >> 6, dd = c2 & 63;
                    int bb = row >> 9, ss = row & 511;
                    if (which == 0) {
                        Cb[((((size_t)bb * NH_ + hh) * S_ + ss) << 6) + dd] =
                            f2b(v * 0.125f);
                    } else if (which == 1) {
                        (Cb + 1048576)[((((size_t)bb * NH_ + hh) * S_ + ss) << 6) + dd] =
                            f2b(v);
                    } else {
                        (Cb + 2097152)[((((size_t)bb * NH_ + hh) * HD_ + dd) << 9) + ss] =
                            f2b(v);
                    }
                } else {
                    if constexpr (FLAGS & FG_POS) v += pos[(size_t)(row & 511) * TN + col];
                    if (extra) v += en;
                    if (resid) v += resid[(size_t)row * TN + col];
                    if constexpr (FLAGS & FG_RELU) v = fmaxf(v, 0.f);
                    if constexpr (FLAGS & FG_BF16)
                        Cb[(size_t)row * TN + col] = f2b(v);
                    if constexpr (FLAGS & FG_F32)
                        Cf[(size_t)row * TN + col] = v;
                }
            }
        }
    }
}

// ---------------------------------------------------------------------------
// Fused flash attention, K/V double-buffered.
// ---------------------------------------------------------------------------
__global__ __launch_bounds__(256) void attn_kernel(
    const ushort* __restrict__ q, const ushort* __restrict__ k,
    const ushort* __restrict__ vT, ushort* __restrict__ pv)
{
    int qt = blockIdx.x, bh = blockIdx.y;
    __shared__ ushort smem[20480];
    ushort* Ps = smem + 16384;
    int t = threadIdx.x, w = t >> 6, lane = t & 63;
    int srow = lane >> 3, slot = lane & 7;
    int gcol = (slot ^ srow) * 8;
    int sl = lane >> 4, lc = lane & 15;

    const ushort* Qp = q + ((size_t)bh * S_ + qt * 64) * HD_;
    const ushort* Kp = k + (size_t)bh * S_ * HD_;
    const ushort* Vp = vT + (size_t)bh * HD_ * S_;

    int qrow = w * 16 + lc;
    bf16x8 qf0 = *reinterpret_cast<const bf16x8*>(Qp + qrow * 64 + sl * 8);
    bf16x8 qf1 = *reinterpret_cast<const bf16x8*>(Qp + qrow * 64 + sl * 8 + 32);

    f32x4 o[4] = {};
    float m_r[4], l_r[4];
    #pragma unroll
    for (int r = 0; r < 4; ++r) { m_r[r] = -1e30f; l_r[r] = 0.f; }
    int row_abs = qt * 64 + w * 16 + sl * 4;

    {
        ushort* Ks = smem;
        ushort* Vs = smem + 4096;
        #pragma unroll
        for (int c = 0; c < 2; ++c) {
            int chunk = w * 2 + c;
            gload16(Kp + (size_t)(chunk * 8 + srow) * 64 + gcol, Ks + chunk * 512);
            gload16(Vp + (size_t)(chunk * 8 + srow) * 512 + gcol, Vs + chunk * 512);
        }
    }

    for (int kt = 0; kt <= qt; ++kt) {
        int cur = kt & 1;
        ushort* Ks = smem + cur * 8192;
        ushort* Vs = smem + cur * 8192 + 4096;
        __syncthreads();
        if (kt < qt) {
            ushort* Kn = smem + (cur ^ 1) * 8192;
            ushort* Vn = Kn + 4096;
            #pragma unroll
            for (int c = 0; c < 2; ++c) {
                int chunk = w * 2 + c;
                gload16(Kp + (size_t)((kt + 1) * 64 + chunk * 8 + srow) * 64 + gcol,
                        Kn + chunk * 512);
                gload16(Vp + (size_t)(chunk * 8 + srow) * 512 + (kt + 1) * 64 + gcol,
                        Vn + chunk * 512);
            }
        }

        f32x4 sa[4] = {};
        #pragma unroll
        for (int n = 0; n < 4; ++n) {
            int rB = n * 16 + lc;
            bf16x8 b0 = *reinterpret_cast<const bf16x8*>(
                Ks + rB * 64 + ((sl ^ (rB & 7)) * 8));
            bf16x8 b1 = *reinterpret_cast<const bf16x8*>(
                Ks + rB * 64 + (((sl + 4) ^ (rB & 7)) * 8));
            sa[n] = __builtin_amdgcn_mfma_f32_16x16x32_bf16(qf0, b0, sa[n], 0, 0, 0);
            sa[n] = __builtin_amdgcn_mfma_f32_16x16x32_bf16(qf1, b1, sa[n], 0, 0, 0);
        }
        if (kt == qt) {
            #pragma unroll
            for (int n = 0; n < 4; ++n) {
                int col = kt * 64 + n * 16 + lc;
                #pragma unroll
                for (int r = 0; r < 4; ++r)
                    if (col > row_abs + r) sa[n][r] = -1e30f;
            }
        }
        float psum[4];
        #pragma unroll
        for (int r = 0; r < 4; ++r) {
            float vm = fmaxf(fmaxf(sa[0][r], sa[1][r]), fmaxf(sa[2][r], sa[3][r]));
            vm = fmaxf(vm, __shfl_xor(vm, 1));
            vm = fmaxf(vm, __shfl_xor(vm, 2));
            vm = fmaxf(vm, __shfl_xor(vm, 4));
            vm = fmaxf(vm, __shfl_xor(vm, 8));
            float mn = fmaxf(m_r[r], vm);
            float scl = __expf(m_r[r] - mn);
            m_r[r] = mn;
            l_r[r] *= scl;
            #pragma unroll
            for (int n = 0; n < 4; ++n) o[n][r] *= scl;
            psum[r] = 0.f;
        }
        ushort* Pw = Ps + w * 1024;
        #pragma unroll
        for (int n = 0; n < 4; ++n) {
            #pragma unroll
            for (int r = 0; r < 4; ++r) {
                float p = __expf(sa[n][r] - m_r[r]);
                psum[r] += p;
                int prow = sl * 4 + r;
                int pcol = n * 16 + lc;
                int pslot = pcol >> 3;
                Pw[prow * 64 + ((pslot ^ (prow & 7)) * 8) + (pcol & 7)] = f2b(p);
            }
        }
        #pragma unroll
        for (int r = 0; r < 4; ++r) {
            float s = psum[r];
            s += __shfl_xor(s, 1);
            s += __shfl_xor(s, 2);
            s += __shfl_xor(s, 4);
            s += __shfl_xor(s, 8);
            l_r[r] += s;
        }
        int arow = lc;
        bf16x8 pa0 = *reinterpret_cast<const bf16x8*>(
            Pw + arow * 64 + ((sl ^ (arow & 7)) * 8));
        bf16x8 pa1 = *reinterpret_cast<const bf16x8*>(
            Pw + arow * 64 + (((sl + 4) ^ (arow & 7)) * 8));
        #pragma unroll
        for (int n = 0; n < 4; ++n) {
            int rB = n * 16 + lc;
            bf16x8 v0 = *reinterpret_cast<const bf16x8*>(
                Vs + rB * 64 + ((sl ^ (rB & 7)) * 8));
            bf16x8 v1 = *reinterpret_cast<const bf16x8*>(
                Vs + rB * 64 + (((sl + 4) ^ (rB & 7)) * 8));
            o[n] = __builtin_amdgcn_mfma_f32_16x16x32_bf16(pa0, v0, o[n], 0, 0, 0);
            o[n] = __builtin_amdgcn_mfma_f32_16x16x32_bf16(pa1, v1, o[n], 0, 0, 0);
        }
    }

    int bb = bh >> 2, hh = bh & 3;
    #pragma unroll
    for (int r = 0; r < 4; ++r) {
        float inv = 1.f / l_r[r];
        int ss = qt * 64 + w * 16 + sl * 4 + r;
        #pragma unroll
        for (int n = 0; n < 4; ++n) {
            int dd = n * 16 + lc;
            pv[((size_t)bb * S_ + ss) * D_ + hh * HD_ + dd] = f2b(o[n][r] * inv);
        }
    }
}

// ===========================================================================
extern "C" void kernel_launch(void* const* d_in, const int* in_sizes, int n_in,
                              void* d_out, int out_size, void* d_ws, size_t ws_size,
                              hipStream_t stream)
{
    const int*   tok     = (const int*)  d_in[0];
    const float* ram     = (const float*)d_in[1];
    const float* proj_W  = (const float*)d_in[2];
    const float* proj_b  = (const float*)d_in[3];
    const float* pos_emb = (const float*)d_in[4];
    const float* sa_Wq   = (const float*)d_in[5];
    const float* sa_Wk   = (const float*)d_in[6];
    const float* sa_Wv   = (const float*)d_in[7];
    const float* sa_Wo   = (const float*)d_in[8];
    const float* sa_bq   = (const float*)d_in[9];
    const float* sa_bk   = (const float*)d_in[10];
    const float* sa_bv   = (const float*)d_in[11];
    const float* sa_bo   = (const float*)d_in[12];
    const float* ca_Wo   = (const float*)d_in[16];
    const float* ca_bv   = (const float*)d_in[19];
    const float* ca_bo   = (const float*)d_in[20];
    const float* ln1_s   = (const float*)d_in[21];
    const float* ln1_b   = (const float*)d_in[22];
    const float* ln3_s   = (const float*)d_in[25];
    const float* ln3_b   = (const float*)d_in[26];
    const float* ff_W1   = (const float*)d_in[27];
    const float* ff_b1   = (const float*)d_in[28];
    const float* ff_W2   = (const float*)d_in[29];
    const float* ff_b2   = (const float*)d_in[30];
    const float* out_W   = (const float*)d_in[31];
    const float* out_b   = (const float*)d_in[32];

    float* out = (float*)d_out;
    float* ws  = (float*)d_ws;

    // ws (must survive to logits): x | cc | xb | Wb
    float*  x   = ws;                            // BS_*D_ f32
    float*  cc  = ws + (size_t)BS_ * D_;         // L_*D_ f32
    ushort* xb  = (ushort*)(cc + L_ * D_);       // BS_*D_ bf16
    ushort* Wb  = xb + (size_t)BS_ * D_;         // V_*D_ bf16

    // d_out scratch (fully overwritten by the logits GEMM)
    ushort* sc_b  = (ushort*)out;                // 2,097,152
    ushort* h_b   = sc_b + 2097152;              // 1,048,576
    ushort* qkv3  = h_b + 1048576;               // 3,145,728 (q|k|vT)
    ushort* pv_b  = qkv3 + 3145728;              // 1,048,576
    ushort* pjWb  = pv_b + 1048576;              // 131,072
    ushort* WqkvB = pjWb + 131072;               // 786,432  [L][768][256]
    ushort* WoB   = WqkvB + 786432;              // 262,144
    ushort* ff1B  = WoB + 262144;                // 524,288
    ushort* ff2B  = ff1B + 524288;               // 524,288
    float*  qkvb  = (float*)(ff2B + 524288);     // 4096 f32 (L*768 used)
    ushort* qb_b  = qkv3;
    ushort* kb_b  = qkv3 + 1048576;
    ushort* vT_b  = qkv3 + 2097152;

    prologue_kernel<<<14276, 256, 0, stream>>>(
        tok, ram, proj_W, sa_Wq, sa_Wk, sa_Wv, sa_Wo, ff_W1, ff_W2, out_W,
        ca_bv, ca_Wo, ca_bo, sa_bq, sa_bk, sa_bv,
        pjWb, WqkvB, WoB, ff1B, ff2B, Wb, cc, qkvb, sc_b);

    // x = scores @ proj_W + proj_b + pos_emb; h_b = ln1_0(x)   (fused)
    gemm_row<512, FG_POS><<<256, 256, 0, stream>>>(
        sc_b, pjWb, proj_b, nullptr, nullptr, pos_emb,
        ln1_s, ln1_b, x, h_b);

    for (int l = 0; l < L_; ++l) {
        gemm_t<64, 64, 256, 768, FG_QKV><<<768, 256, 0, stream>>>(
            h_b, WqkvB + (size_t)l * 196608, qkvb + l * 768,
            nullptr, nullptr, nullptr, nullptr, qkv3);
        attn_kernel<<<dim3(8, 32), 256, 0, stream>>>(qb_b, kb_b, vT_b, pv_b);
        // fused tail: o-proj + resid + cc + LN3 + FF + resid (+ LN1next | xb)
        if (l < L_ - 1) {
            tail_fused_kernel<false><<<256, 256, 0, stream>>>(
                pv_b, WoB + (size_t)l * 65536, sa_bo + l * D_, cc + l * D_, x,
                ln3_s + l * D_, ln3_b + l * D_,
                ff1B + (size_t)l * 131072, ff2B + (size_t)l * 131072,
                ff_b1 + l * FF_, ff_b2 + l * D_,
                ln1_s + (l + 1) * D_, ln1_b + (l + 1) * D_, x, h_b, nullptr);
        } else {
            tail_fused_kernel<true><<<256, 256, 0, stream>>>(
                pv_b, WoB + (size_t)l * 65536, sa_bo + l * D_, cc + l * D_, x,
                ln3_s + l * D_, ln3_b + l * D_,
                ff1B + (size_t)l * 131072, ff2B + (size_t)l * 131072,
                ff_b1 + l * FF_, ff_b2 + l * D_,
                nullptr, nullptr, nullptr, nullptr, xb);
        }
    }

    // logits = xb @ Wb^T + out_b  (overwrites all of d_out)
    gemm_t<128, 128, 256, 32000, FG_F32 | FG_NT><<<8000, 256, 0, stream>>>(
        xb, Wb, out_b, nullptr, nullptr, nullptr, out, nullptr);
}